// Round 1
// baseline (651.414 us; speedup 1.0000x reference)
//
#include <hip/hip_runtime.h>

typedef unsigned short u16;
typedef unsigned int   u32;
typedef __attribute__((ext_vector_type(8))) short short8;
typedef __attribute__((ext_vector_type(4))) float f32x4;

__device__ __forceinline__ u16 f2b(float f) {
  u32 u = __float_as_uint(f);
  return (u16)((u + 0x7FFFu + ((u >> 16) & 1u)) >> 16);
}
__device__ __forceinline__ float b2f(u16 b) { return __uint_as_float((u32)b << 16); }
__device__ __forceinline__ u32 pack2(float a, float b) {
  return (u32)f2b(a) | ((u32)f2b(b) << 16);
}

#define GLDS16(gp, lp) __builtin_amdgcn_global_load_lds( \
    (const __attribute__((address_space(1))) u32*)(gp), \
    (__attribute__((address_space(3))) u32*)(lp), 16, 0, 0)

// ---------------- dims ----------------
// b=2 c=512 t=16 h=32 w=32 ; BT=32 N=1024 ROWS=32768 heads=8 d=64
#define ROWS 32768
#define CO3  1536

// ---------------- ws offsets (bytes) ----------------
#define OFF_WSQKV 0UL
#define OFF_WSOUT (OFF_WSQKV + 1536UL*512*2)
#define OFF_WTQKV (OFF_WSOUT + 512UL*512*2)
#define OFF_WTOUT (OFF_WTQKV + 1536UL*512*2)
#define OFF_KST   (OFF_WTOUT + 512UL*512*2)
#define OFF_CTXT  (OFF_KST   + 256UL*64*8)
#define OFF_XT    (OFF_CTXT  + 256UL*64*64*2)
#define OFF_QKV   (OFF_XT    + 32768UL*512*2)
#define OFF_MID   (OFF_QKV   + 32768UL*1536*2)
#define OFF_MIDB  (OFF_MID   + 32768UL*512*2)

// ---------------- weight f32 -> bf16 ----------------
__global__ __launch_bounds__(256) void k_cvtw(const float* ws, const float* wso,
                                              const float* wt, const float* wto,
                                              u16* o1, u16* o2, u16* o3, u16* o4) {
  int i = blockIdx.x * 256 + threadIdx.x;
  if (i < 786432) { o1[i] = f2b(ws[i]); o3[i] = f2b(wt[i]); }
  if (i < 262144) { o2[i] = f2b(wso[i]); o4[i] = f2b(wto[i]); }
}

// ---------------- x (b,c,t,n) f32 -> xT [bt*N+n][c] bf16 ----------------
__global__ __launch_bounds__(256) void k_xT(const float* __restrict__ x, u16* __restrict__ xT) {
  __shared__ u16 tile[64 * 65]; // [c][n]
  int bt = blockIdx.x, c0 = blockIdx.y * 64, n0 = blockIdx.z * 64;
  int b = bt >> 4, t = bt & 15;
  int tid = threadIdx.x;
  const size_t xoff = ((size_t)(b * 512 + c0) * 16 + t) * 1024 + n0;
  #pragma unroll
  for (int it = 0; it < 16; ++it) {
    int cl = it * 4 + (tid >> 6), nl = tid & 63;
    tile[cl * 65 + nl] = f2b(x[xoff + (size_t)cl * 16384 + nl]);
  }
  __syncthreads();
  int nl = tid >> 2, cs = (tid & 3) * 16;
  u32 uu[8];
  #pragma unroll
  for (int j = 0; j < 8; ++j) {
    u32 lo = tile[(cs + j * 2) * 65 + nl];
    u32 hi = tile[(cs + j * 2 + 1) * 65 + nl];
    uu[j] = lo | (hi << 16);
  }
  u16* dst = xT + (size_t)(bt * 1024 + n0 + nl) * 512 + c0 + cs;
  ((uint4*)dst)[0] = make_uint4(uu[0], uu[1], uu[2], uu[3]);
  ((uint4*)dst)[1] = make_uint4(uu[4], uu[5], uu[6], uu[7]);
}

// ---------------- GEMM: C[row][o] = sum_c A[row][c]*B[o][c] (+bias) ----------------
// A [Mtot][512] bf16, B [NOUT][512] bf16, C [Mtot][NOUT] bf16. 128x128 tile, BK=64.
template <int NOUT, int BIAS>
__global__ __launch_bounds__(256) void gemm_cl(const u16* __restrict__ A, const u16* __restrict__ B,
                                               const float* __restrict__ bias, u16* __restrict__ C) {
  __shared__ u16 At[128 * 64];
  __shared__ u16 Bt[128 * 64];
  const int bm = blockIdx.x, bn = blockIdx.y;
  const int tid = threadIdx.x;
  const int w = tid >> 6, lane = tid & 63;
  const int wm = w >> 1, wn = w & 1;
  const int arow0 = bm * 128;
  const int brow0 = bn * 128;
  const int srow = lane >> 3;          // 0..7
  const int scol = (lane & 7) * 8;     // elem col within 64
  f32x4 acc[4][4] = {};
  for (int kt = 0; kt < 8; ++kt) {
    __syncthreads();
    const int k0 = kt * 64;
    #pragma unroll
    for (int i = 0; i < 4; ++i) {
      int q = w * 4 + i;
      int r = q * 8 + srow;
      GLDS16(A + (size_t)(arow0 + r) * 512 + k0 + scol, &At[q * 512]);
      GLDS16(B + (size_t)(brow0 + r) * 512 + k0 + scol, &Bt[q * 512]);
    }
    __syncthreads();
    const int fr = lane & 15, fq = lane >> 4;
    #pragma unroll
    for (int ks = 0; ks < 2; ++ks) {
      short8 af[4], bf[4];
      #pragma unroll
      for (int m = 0; m < 4; ++m)
        af[m] = *(const short8*)&At[(wm * 64 + m * 16 + fr) * 64 + ks * 32 + fq * 8];
      #pragma unroll
      for (int n = 0; n < 4; ++n)
        bf[n] = *(const short8*)&Bt[(wn * 64 + n * 16 + fr) * 64 + ks * 32 + fq * 8];
      #pragma unroll
      for (int m = 0; m < 4; ++m)
        #pragma unroll
        for (int n = 0; n < 4; ++n)
          acc[m][n] = __builtin_amdgcn_mfma_f32_16x16x32_bf16(af[m], bf[n], acc[m][n], 0, 0, 0);
    }
  }
  const int fr = lane & 15, fq = lane >> 4;
  #pragma unroll
  for (int m = 0; m < 4; ++m) {
    int row = arow0 + wm * 64 + m * 16 + fq * 4;
    #pragma unroll
    for (int n = 0; n < 4; ++n) {
      int col = bn * 128 + wn * 64 + n * 16 + fr;
      float bv = BIAS ? bias[col] : 0.0f;
      u16* cp = C + (size_t)row * NOUT + col;
      #pragma unroll
      for (int r = 0; r < 4; ++r)
        cp[(size_t)r * NOUT] = f2b(acc[m][n][r] + bv);
    }
  }
}

// ---------------- spatial q softmax over d (in-place, * 1/8) ----------------
__global__ __launch_bounds__(256) void k_qsoft(u16* __restrict__ qkv) {
  int gid = blockIdx.x * 256 + threadIdx.x;  // 262144 = 32768 rows * 8 heads
  int row = gid >> 3, h = gid & 7;
  u16* p = qkv + (size_t)row * 1536 + h * 64;
  uint4 raw[8];
  #pragma unroll
  for (int i = 0; i < 8; ++i) raw[i] = ((const uint4*)p)[i];
  float v[64];
  #pragma unroll
  for (int i = 0; i < 8; ++i) {
    u32 u0 = raw[i].x, u1 = raw[i].y, u2 = raw[i].z, u3 = raw[i].w;
    v[i*8+0] = __uint_as_float(u0 << 16); v[i*8+1] = __uint_as_float(u0 & 0xffff0000u);
    v[i*8+2] = __uint_as_float(u1 << 16); v[i*8+3] = __uint_as_float(u1 & 0xffff0000u);
    v[i*8+4] = __uint_as_float(u2 << 16); v[i*8+5] = __uint_as_float(u2 & 0xffff0000u);
    v[i*8+6] = __uint_as_float(u3 << 16); v[i*8+7] = __uint_as_float(u3 & 0xffff0000u);
  }
  float mx = v[0];
  #pragma unroll
  for (int i = 1; i < 64; ++i) mx = fmaxf(mx, v[i]);
  float s = 0.f;
  #pragma unroll
  for (int i = 0; i < 64; ++i) { v[i] = __expf(v[i] - mx); s += v[i]; }
  float inv = 0.125f / s;
  #pragma unroll
  for (int i = 0; i < 64; ++i) v[i] *= inv;
  #pragma unroll
  for (int i = 0; i < 8; ++i) {
    uint4 o = make_uint4(pack2(v[i*8+0], v[i*8+1]), pack2(v[i*8+2], v[i*8+3]),
                         pack2(v[i*8+4], v[i*8+5]), pack2(v[i*8+6], v[i*8+7]));
    ((uint4*)p)[i] = o;
  }
}

// ---------------- spatial k stats: per (bt,h,d): max over n, 1/sum(exp) ----------------
__global__ __launch_bounds__(256) void k_kstats(const u16* __restrict__ qkv, float2* __restrict__ kst) {
  __shared__ float sm[4][64];
  int bh = blockIdx.x; int bt = bh >> 3, h = bh & 7;
  int tid = threadIdx.x; int wv = tid >> 6, l = tid & 63;
  const u16* base = qkv + (size_t)(bt * 1024) * 1536 + 512 + h * 64 + l;
  float mx = -1e30f;
  for (int n = wv; n < 1024; n += 4) mx = fmaxf(mx, b2f(base[(size_t)n * 1536]));
  sm[wv][l] = mx; __syncthreads();
  float M = fmaxf(fmaxf(sm[0][l], sm[1][l]), fmaxf(sm[2][l], sm[3][l]));
  __syncthreads();
  float z = 0.f;
  for (int n = wv; n < 1024; n += 4) z += __expf(b2f(base[(size_t)n * 1536]) - M);
  sm[wv][l] = z; __syncthreads();
  if (wv == 0) {
    float Z = sm[0][l] + sm[1][l] + sm[2][l] + sm[3][l];
    kst[bh * 64 + l] = make_float2(M, 1.0f / Z);
  }
}

// ---------------- ctx[d][e] = sum_n softmax_n(k)[d][n] * v[e][n] ; writes ctxT[e][d] bf16 ----------------
__global__ __launch_bounds__(256) void k_ctx(const u16* __restrict__ qkv, const float2* __restrict__ kst,
                                             u16* __restrict__ ctxT) {
  __shared__ u16 Kc[64 * 64];
  __shared__ u16 Vc[64 * 64];
  __shared__ float Ek[64 * 64];
  __shared__ float Ms[64], Zs[64];
  int bh = blockIdx.x; int bt = bh >> 3, h = bh & 7;
  int tid = threadIdx.x;
  if (tid < 64) { float2 mz = kst[bh * 64 + tid]; Ms[tid] = mz.x; Zs[tid] = mz.y; }
  int td = tid & 15, te = tid >> 4;
  int d0 = td * 4, e0 = te * 4;
  float acc[4][4] = {};
  int r = tid >> 2, part = tid & 3;
  int colbase = (part < 2) ? (512 + h * 64 + part * 32) : (1024 + h * 64 + (part - 2) * 32);
  u16* ldst = (part < 2) ? &Kc[r * 64 + part * 32] : &Vc[r * 64 + (part - 2) * 32];
  for (int ch = 0; ch < 16; ++ch) {
    __syncthreads();
    int n0 = ch * 64;
    const uint4* src = (const uint4*)(qkv + (size_t)(bt * 1024 + n0 + r) * 1536 + colbase);
    uint4* dst = (uint4*)ldst;
    #pragma unroll
    for (int i = 0; i < 4; ++i) dst[i] = src[i];
    __syncthreads();
    {
      int nn = tid >> 2, dbase = (tid & 3) * 16;
      #pragma unroll
      for (int ii = 0; ii < 16; ++ii) {
        int d = dbase + ii;
        Ek[nn * 64 + d] = __expf(b2f(Kc[nn * 64 + d]) - Ms[d]) * Zs[d];
      }
    }
    __syncthreads();
    #pragma unroll 2
    for (int n = 0; n < 64; ++n) {
      float4 ek = *(const float4*)&Ek[n * 64 + d0];
      float ekf[4] = {ek.x, ek.y, ek.z, ek.w};
      ushort4 vv = *(const ushort4*)&Vc[n * 64 + e0];
      float vf[4] = {b2f(vv.x), b2f(vv.y), b2f(vv.z), b2f(vv.w)};
      #pragma unroll
      for (int i = 0; i < 4; ++i)
        #pragma unroll
        for (int j = 0; j < 4; ++j)
          acc[i][j] += ekf[i] * vf[j];
    }
  }
  #pragma unroll
  for (int j = 0; j < 4; ++j)
    #pragma unroll
    for (int i = 0; i < 4; ++i)
      ctxT[(size_t)bh * 4096 + (e0 + j) * 64 + d0 + i] = f2b(acc[i][j]);
}

// ---------------- out1T[row][h*64+e] = sum_d qs[row][h*64+d] * ctx[d][e]  (MFMA) ----------------
__global__ __launch_bounds__(256) void k_apply(const u16* __restrict__ qkv, const u16* __restrict__ ctxT,
                                               u16* __restrict__ out1) {
  __shared__ u16 ct[64 * 72]; // ctxT[e][d], padded stride 72
  int bh = blockIdx.x; int bt = bh >> 3, h = bh & 7;
  int tid = threadIdx.x; int w = tid >> 6, lane = tid & 63;
  {
    int e = tid >> 2, db = (tid & 3) * 16;
    const uint4* s = (const uint4*)&ctxT[(size_t)bh * 4096 + e * 64 + db];
    *(uint4*)&ct[e * 72 + db] = s[0];
    *(uint4*)&ct[e * 72 + db + 8] = s[1];
  }
  __syncthreads();
  int fr = lane & 15, fq = lane >> 4;
  short8 bfrag[4][2];
  #pragma unroll
  for (int n = 0; n < 4; ++n)
    #pragma unroll
    for (int ks = 0; ks < 2; ++ks)
      bfrag[n][ks] = *(const short8*)&ct[(n * 16 + fr) * 72 + ks * 32 + fq * 8];
  const u16* qbase = qkv + (size_t)(bt * 1024 + w * 256) * 1536 + h * 64;
  for (int mt = 0; mt < 16; ++mt) {
    f32x4 acc[4] = {};
    short8 af[2];
    #pragma unroll
    for (int ks = 0; ks < 2; ++ks)
      af[ks] = *(const short8*)(qbase + (size_t)(mt * 16 + fr) * 1536 + ks * 32 + fq * 8);
    #pragma unroll
    for (int ks = 0; ks < 2; ++ks)
      #pragma unroll
      for (int n = 0; n < 4; ++n)
        acc[n] = __builtin_amdgcn_mfma_f32_16x16x32_bf16(af[ks], bfrag[n][ks], acc[n], 0, 0, 0);
    #pragma unroll
    for (int n = 0; n < 4; ++n) {
      #pragma unroll
      for (int r2 = 0; r2 < 4; ++r2) {
        int row = bt * 1024 + w * 256 + mt * 16 + fq * 4 + r2;
        out1[(size_t)row * 512 + h * 64 + n * 16 + fr] = f2b(acc[n][r2]);
      }
    }
  }
}

// ---------------- temporal attention: per (b,s): 8 heads, 16x16 attn over t, d=64 ----------------
__global__ __launch_bounds__(128) void k_tattn(const u16* __restrict__ qkvt, u16* __restrict__ outbuf) {
  __shared__ u16 L[16 * 1536];
  int bs = blockIdx.x;
  int b = bs >> 10, s = bs & 1023;
  int tid = threadIdx.x;
  {
    int row = tid >> 3, seg = tid & 7;
    const uint4* src = (const uint4*)(qkvt + ((size_t)((b * 16 + row) * 1024 + s)) * 1536 + seg * 192);
    uint4* dst = (uint4*)(L + row * 1536 + seg * 192);
    #pragma unroll
    for (int i = 0; i < 24; ++i) dst[i] = src[i];
  }
  __syncthreads();
  int h = tid >> 4, i = tid & 15;
  const u16* qrow = L + i * 1536 + h * 64;
  float qf[64];
  #pragma unroll
  for (int c = 0; c < 16; ++c) {
    ushort4 u = *(const ushort4*)(qrow + c * 4);
    qf[c*4+0] = b2f(u.x); qf[c*4+1] = b2f(u.y); qf[c*4+2] = b2f(u.z); qf[c*4+3] = b2f(u.w);
  }
  float sim[16];
  #pragma unroll 1
  for (int j = 0; j < 16; ++j) {
    const u16* krow = L + j * 1536 + 512 + h * 64;
    float acc = 0.f;
    #pragma unroll
    for (int c = 0; c < 16; ++c) {
      ushort4 u = *(const ushort4*)(krow + c * 4);
      acc += qf[c*4+0]*b2f(u.x) + qf[c*4+1]*b2f(u.y) + qf[c*4+2]*b2f(u.z) + qf[c*4+3]*b2f(u.w);
    }
    sim[j] = acc * 0.125f;
  }
  float mx = sim[0];
  #pragma unroll
  for (int j = 1; j < 16; ++j) mx = fmaxf(mx, sim[j]);
  float ssum = 0.f;
  #pragma unroll
  for (int j = 0; j < 16; ++j) { sim[j] = __expf(sim[j] - mx); ssum += sim[j]; }
  float inv = 1.0f / ssum;
  float outv[64];
  #pragma unroll
  for (int d = 0; d < 64; ++d) outv[d] = 0.f;
  #pragma unroll 1
  for (int j = 0; j < 16; ++j) {
    float a = sim[j] * inv;
    const u16* vrow = L + j * 1536 + 1024 + h * 64;
    #pragma unroll
    for (int c = 0; c < 16; ++c) {
      ushort4 u = *(const ushort4*)(vrow + c * 4);
      outv[c*4+0] += a * b2f(u.x); outv[c*4+1] += a * b2f(u.y);
      outv[c*4+2] += a * b2f(u.z); outv[c*4+3] += a * b2f(u.w);
    }
  }
  u16* dst = outbuf + ((size_t)((b * 16 + i) * 1024 + s)) * 512 + h * 64;
  #pragma unroll
  for (int c = 0; c < 8; ++c) {
    uint4 o = make_uint4(pack2(outv[c*8+0], outv[c*8+1]), pack2(outv[c*8+2], outv[c*8+3]),
                         pack2(outv[c*8+4], outv[c*8+5]), pack2(outv[c*8+6], outv[c*8+7]));
    ((uint4*)dst)[c] = o;
  }
}

// ---------------- final: out(b,c,t,n) = x + transpose(h2T) ----------------
__global__ __launch_bounds__(256) void k_final(const float* __restrict__ x, const u16* __restrict__ h2T,
                                               float* __restrict__ out) {
  __shared__ u16 tile[64 * 65]; // [c][n]
  int bt = blockIdx.x, c0 = blockIdx.y * 64, n0 = blockIdx.z * 64;
  int b = bt >> 4, t = bt & 15;
  int tid = threadIdx.x;
  {
    int nl = tid >> 2, cs = (tid & 3) * 16;
    const u16* src = h2T + (size_t)(bt * 1024 + n0 + nl) * 512 + c0 + cs;
    uint4 a = ((const uint4*)src)[0], bb = ((const uint4*)src)[1];
    u32 uu[8] = {a.x, a.y, a.z, a.w, bb.x, bb.y, bb.z, bb.w};
    #pragma unroll
    for (int j = 0; j < 8; ++j) {
      tile[(cs + j * 2) * 65 + nl]     = (u16)(uu[j] & 0xffffu);
      tile[(cs + j * 2 + 1) * 65 + nl] = (u16)(uu[j] >> 16);
    }
  }
  __syncthreads();
  const size_t xoff = ((size_t)(b * 512 + c0) * 16 + t) * 1024 + n0;
  #pragma unroll
  for (int it = 0; it < 16; ++it) {
    int cl = it * 4 + (tid >> 6), nl = tid & 63;
    size_t o = xoff + (size_t)cl * 16384 + nl;
    out[o] = x[o] + b2f(tile[cl * 65 + nl]);
  }
}

extern "C" void kernel_launch(void* const* d_in, const int* in_sizes, int n_in,
                              void* d_out, int out_size, void* d_ws, size_t ws_size,
                              hipStream_t stream) {
  const float* x      = (const float*)d_in[0];
  const float* w_sqkv = (const float*)d_in[1];
  const float* w_sout = (const float*)d_in[2];
  const float* b_sout = (const float*)d_in[3];
  const float* w_tqkv = (const float*)d_in[4];
  const float* w_tout = (const float*)d_in[5];
  float* out = (float*)d_out;
  char* ws = (char*)d_ws;

  u16* wsqkv_b = (u16*)(ws + OFF_WSQKV);
  u16* wsout_b = (u16*)(ws + OFF_WSOUT);
  u16* wtqkv_b = (u16*)(ws + OFF_WTQKV);
  u16* wtout_b = (u16*)(ws + OFF_WTOUT);
  float2* kst  = (float2*)(ws + OFF_KST);
  u16* ctxT    = (u16*)(ws + OFF_CTXT);
  u16* xT      = (u16*)(ws + OFF_XT);   // later reused as h2T
  u16* qkv     = (u16*)(ws + OFF_QKV);  // spatial qkv, later temporal qkv
  u16* mid     = (u16*)(ws + OFF_MID);  // out1T, later attout
  u16* midB    = (u16*)(ws + OFF_MIDB); // h1T

  k_cvtw<<<3072, 256, 0, stream>>>(w_sqkv, w_sout, w_tqkv, w_tout, wsqkv_b, wsout_b, wtqkv_b, wtout_b);
  k_xT<<<dim3(32, 8, 16), 256, 0, stream>>>(x, xT);
  gemm_cl<1536, 0><<<dim3(256, 12), 256, 0, stream>>>(xT, wsqkv_b, nullptr, qkv);
  k_qsoft<<<1024, 256, 0, stream>>>(qkv);
  k_kstats<<<256, 256, 0, stream>>>(qkv, kst);
  k_ctx<<<256, 256, 0, stream>>>(qkv, kst, ctxT);
  k_apply<<<256, 256, 0, stream>>>(qkv, ctxT, mid);
  gemm_cl<512, 1><<<dim3(256, 4), 256, 0, stream>>>(mid, wsout_b, b_sout, midB);
  gemm_cl<1536, 0><<<dim3(256, 12), 256, 0, stream>>>(midB, wtqkv_b, nullptr, qkv);
  k_tattn<<<2048, 128, 0, stream>>>(qkv, mid);
  gemm_cl<512, 0><<<dim3(256, 4), 256, 0, stream>>>(mid, wtout_b, nullptr, xT);
  k_final<<<dim3(32, 8, 16), 256, 0, stream>>>(x, xT, out);
}

// Round 2
// 500.387 us; speedup vs baseline: 1.3018x; 1.3018x over previous
//
#include <hip/hip_runtime.h>

typedef unsigned short u16;
typedef unsigned int   u32;
typedef __attribute__((ext_vector_type(8))) short short8;
typedef __attribute__((ext_vector_type(4))) float f32x4;

__device__ __forceinline__ u16 f2b(float f) {
  u32 u = __float_as_uint(f);
  return (u16)((u + 0x7FFFu + ((u >> 16) & 1u)) >> 16);
}
__device__ __forceinline__ float b2f(u16 b) { return __uint_as_float((u32)b << 16); }
__device__ __forceinline__ u32 pack2(float a, float b) {
  return (u32)f2b(a) | ((u32)f2b(b) << 16);
}

#define GLDS16(gp, lp) __builtin_amdgcn_global_load_lds( \
    (const __attribute__((address_space(1))) u32*)(gp), \
    (__attribute__((address_space(3))) u32*)(lp), 16, 0, 0)

// ---------------- dims ----------------
// b=2 c=512 t=16 h=32 w=32 ; BT=32 N=1024 ROWS=32768 heads=8 d=64

// ---------------- ws offsets (bytes) ----------------
#define OFF_WSQKV 0UL
#define OFF_WSOUT (OFF_WSQKV + 1536UL*512*2)
#define OFF_WTQKV (OFF_WSOUT + 512UL*512*2)
#define OFF_WTOUT (OFF_WTQKV + 1536UL*512*2)
#define OFF_KST   (OFF_WTOUT + 512UL*512*2)
#define OFF_CTXT  (OFF_KST   + 256UL*64*8)
#define OFF_XT    (OFF_CTXT  + 256UL*64*64*2)
#define OFF_QKV   (OFF_XT    + 32768UL*512*2)
#define OFF_MID   (OFF_QKV   + 32768UL*1536*2)
#define OFF_MIDB  (OFF_MID   + 32768UL*512*2)
#define OFF_PART  (OFF_MIDB  + 32768UL*512*2)

// ---------------- weight f32 -> bf16 ----------------
__global__ __launch_bounds__(256) void k_cvtw(const float* ws, const float* wso,
                                              const float* wt, const float* wto,
                                              u16* o1, u16* o2, u16* o3, u16* o4) {
  int i = blockIdx.x * 256 + threadIdx.x;
  if (i < 786432) { o1[i] = f2b(ws[i]); o3[i] = f2b(wt[i]); }
  if (i < 262144) { o2[i] = f2b(wso[i]); o4[i] = f2b(wto[i]); }
}

// ---------------- x (b,c,t,n) f32 -> xT [bt*N+n][c] bf16 ----------------
__global__ __launch_bounds__(256) void k_xT(const float* __restrict__ x, u16* __restrict__ xT) {
  __shared__ u16 tile[64 * 65]; // [c][n]
  int bt = blockIdx.x, c0 = blockIdx.y * 64, n0 = blockIdx.z * 64;
  int b = bt >> 4, t = bt & 15;
  int tid = threadIdx.x;
  const size_t xoff = ((size_t)(b * 512 + c0) * 16 + t) * 1024 + n0;
  #pragma unroll
  for (int it = 0; it < 16; ++it) {
    int cl = it * 4 + (tid >> 6), nl = tid & 63;
    tile[cl * 65 + nl] = f2b(x[xoff + (size_t)cl * 16384 + nl]);
  }
  __syncthreads();
  int nl = tid >> 2, cs = (tid & 3) * 16;
  u32 uu[8];
  #pragma unroll
  for (int j = 0; j < 8; ++j) {
    u32 lo = tile[(cs + j * 2) * 65 + nl];
    u32 hi = tile[(cs + j * 2 + 1) * 65 + nl];
    uu[j] = lo | (hi << 16);
  }
  u16* dst = xT + (size_t)(bt * 1024 + n0 + nl) * 512 + c0 + cs;
  ((uint4*)dst)[0] = make_uint4(uu[0], uu[1], uu[2], uu[3]);
  ((uint4*)dst)[1] = make_uint4(uu[4], uu[5], uu[6], uu[7]);
}

// ---------------- 8-phase 256x256 GEMM: C[row][o] = sum_c A[row][c]*B[o][c] (+bias) ----------------
// A [Mtot][512] bf16, B [NOUT][512] bf16, C [Mtot][NOUT] bf16.
// LDS layout: [buf][mat(A=0,B=1)][ks] regions of 256 rows x 32 cols bf16 (16KB each), 128KB total.
// Swizzle: physical 16B-slot = logical_slot ^ ((row>>1)&3)  (applied on global src + ds_read).
template <int NOUT, int BIAS>
__global__ __launch_bounds__(512, 2) void gemm8(const u16* __restrict__ A, const u16* __restrict__ B,
                                                const float* __restrict__ bias, u16* __restrict__ C) {
  __shared__ u16 lds[65536];
  const int tid = threadIdx.x;
  const int wid = tid >> 6, lane = tid & 63;
  const int wm = wid >> 2, wn = wid & 3;
  const int fr = lane & 15, fq = lane >> 4;
  const int bm = blockIdx.x, bn = blockIdx.y;
  const long arow0 = (long)bm * 256, brow0 = (long)bn * 256;

  const int srow  = wid * 16 + (lane >> 2);                 // row 0..127 within load chunk
  const int scol8 = ((lane & 3) ^ ((lane >> 3) & 3)) * 8;   // pre-swizzled col element within 32-col half
  const int rslot = (fq ^ ((fr >> 1) & 3)) * 8;             // swizzled read slot (u16 units)

  auto stage = [&](int mat, int bfi, int s, int kt) {
    const u16* src = (mat == 0 ? A + (arow0 + srow) * 512 : B + (brow0 + srow) * 512)
                     + kt * 64 + s * 32 + scol8;
    int off = ((bfi * 2 + mat) * 2 + s) * 8192 + wid * 512;
    GLDS16(src, &lds[off]);
    GLDS16(src + 128 * 512, &lds[off + 4096]);
  };
  auto ldA = [&](int bfi, int s, int m) -> short8 {
    int row = wm * 128 + m * 16 + fr;
    return *(const short8*)&lds[((bfi * 2 + 0) * 2 + s) * 8192 + row * 32 + rslot];
  };
  auto ldB = [&](int bfi, int s, int n) -> short8 {
    int row = wn * 64 + n * 16 + fr;
    return *(const short8*)&lds[((bfi * 2 + 1) * 2 + s) * 8192 + row * 32 + rslot];
  };

  f32x4 acc[8][4] = {};
  short8 af[8]; short8 bf0, bf1;

  // prologue: buf0 <- K-tile 0 (A-ks0, B-ks0, A-ks1, B-ks1); buf1 <- K-tile 1 (A-ks0, B-ks0, A-ks1)
  stage(0, 0, 0, 0); stage(1, 0, 0, 0); stage(0, 0, 1, 0); stage(1, 0, 1, 0);
  stage(0, 1, 0, 1); stage(1, 1, 0, 1); stage(0, 1, 1, 1);
  asm volatile("s_waitcnt vmcnt(4)" ::: "memory");
  asm volatile("" ::: "memory");
  __builtin_amdgcn_s_barrier();

#define PHASE(BUFI, S, NH, READ_A, SM, SB, SS, SKT, DO_VM)                          \
  {                                                                                 \
    if (READ_A) { _Pragma("unroll") for (int m = 0; m < 8; ++m) af[m] = ldA(BUFI, S, m); } \
    bf0 = ldB(BUFI, S, (NH)*2); bf1 = ldB(BUFI, S, (NH)*2 + 1);                     \
    stage(SM, SB, SS, SKT);                                                         \
    asm volatile("" ::: "memory");                                                  \
    __builtin_amdgcn_s_barrier();                                                   \
    asm volatile("s_waitcnt lgkmcnt(0)" ::: "memory");                              \
    __builtin_amdgcn_sched_barrier(0);                                              \
    __builtin_amdgcn_s_setprio(1);                                                  \
    _Pragma("unroll") for (int m = 0; m < 8; ++m) {                                 \
      acc[m][(NH)*2]   = __builtin_amdgcn_mfma_f32_16x16x32_bf16(af[m], bf0, acc[m][(NH)*2], 0, 0, 0);     \
      acc[m][(NH)*2+1] = __builtin_amdgcn_mfma_f32_16x16x32_bf16(af[m], bf1, acc[m][(NH)*2+1], 0, 0, 0);   \
    }                                                                               \
    __builtin_amdgcn_s_setprio(0);                                                  \
    if (DO_VM) asm volatile("s_waitcnt vmcnt(4)" ::: "memory");                     \
    asm volatile("" ::: "memory");                                                  \
    __builtin_amdgcn_s_barrier();                                                   \
  }

  for (int i = 0; i < 4; ++i) {
    const int kb = 2 * i;
    const int k1 = kb + 1;
    const int k2 = (kb + 2 < 8) ? kb + 2 : 7;
    const int k3 = (kb + 3 < 8) ? kb + 3 : 7;
    PHASE(0, 0, 0, 1, 1, 1, 1, k1, 0)  // ph1: compute buf0/ks0/n01; stage buf1.B-ks1 <- k1
    PHASE(0, 0, 1, 0, 0, 0, 0, k2, 0)  // ph2: buf0/ks0/n23; stage buf0.A-ks0 <- k2
    PHASE(0, 1, 0, 1, 1, 0, 0, k2, 0)  // ph3: buf0/ks1/n01; stage buf0.B-ks0 <- k2
    PHASE(0, 1, 1, 0, 0, 0, 1, k2, 1)  // ph4: buf0/ks1/n23; stage buf0.A-ks1 <- k2; vmcnt(4)
    PHASE(1, 0, 0, 1, 1, 0, 1, k2, 0)  // ph5: buf1/ks0/n01; stage buf0.B-ks1 <- k2
    PHASE(1, 0, 1, 0, 0, 1, 0, k3, 0)  // ph6: buf1/ks0/n23; stage buf1.A-ks0 <- k3
    PHASE(1, 1, 0, 1, 1, 1, 0, k3, 0)  // ph7: buf1/ks1/n01; stage buf1.B-ks0 <- k3
    PHASE(1, 1, 1, 0, 0, 1, 1, k3, 1)  // ph8: buf1/ks1/n23; stage buf1.A-ks1 <- k3; vmcnt(4)
  }
#undef PHASE

  #pragma unroll
  for (int m = 0; m < 8; ++m) {
    long row = arow0 + wm * 128 + m * 16 + fq * 4;
    #pragma unroll
    for (int n = 0; n < 4; ++n) {
      long col = brow0 + wn * 64 + n * 16 + fr;
      float bv = BIAS ? bias[col] : 0.0f;
      u16* cp = C + (size_t)row * NOUT + col;
      #pragma unroll
      for (int r = 0; r < 4; ++r)
        cp[(size_t)r * NOUT] = f2b(acc[m][n][r] + bv);
    }
  }
}

// ---------------- spatial q softmax over d (in-place, * 1/8) ----------------
__global__ __launch_bounds__(256) void k_qsoft(u16* __restrict__ qkv) {
  int gid = blockIdx.x * 256 + threadIdx.x;  // 262144 = 32768 rows * 8 heads
  int row = gid >> 3, h = gid & 7;
  u16* p = qkv + (size_t)row * 1536 + h * 64;
  uint4 raw[8];
  #pragma unroll
  for (int i = 0; i < 8; ++i) raw[i] = ((const uint4*)p)[i];
  float v[64];
  #pragma unroll
  for (int i = 0; i < 8; ++i) {
    u32 u0 = raw[i].x, u1 = raw[i].y, u2 = raw[i].z, u3 = raw[i].w;
    v[i*8+0] = __uint_as_float(u0 << 16); v[i*8+1] = __uint_as_float(u0 & 0xffff0000u);
    v[i*8+2] = __uint_as_float(u1 << 16); v[i*8+3] = __uint_as_float(u1 & 0xffff0000u);
    v[i*8+4] = __uint_as_float(u2 << 16); v[i*8+5] = __uint_as_float(u2 & 0xffff0000u);
    v[i*8+6] = __uint_as_float(u3 << 16); v[i*8+7] = __uint_as_float(u3 & 0xffff0000u);
  }
  float mx = v[0];
  #pragma unroll
  for (int i = 1; i < 64; ++i) mx = fmaxf(mx, v[i]);
  float s = 0.f;
  #pragma unroll
  for (int i = 0; i < 64; ++i) { v[i] = __expf(v[i] - mx); s += v[i]; }
  float inv = 0.125f / s;
  #pragma unroll
  for (int i = 0; i < 64; ++i) v[i] *= inv;
  #pragma unroll
  for (int i = 0; i < 8; ++i) {
    uint4 o = make_uint4(pack2(v[i*8+0], v[i*8+1]), pack2(v[i*8+2], v[i*8+3]),
                         pack2(v[i*8+4], v[i*8+5]), pack2(v[i*8+6], v[i*8+7]));
    ((uint4*)p)[i] = o;
  }
}

// ---------------- spatial k stats: online per-column max/sumexp, coalesced ----------------
// grid (32 bt, 8 q), 512 threads: thread c handles k-column c for 128 rows.
__global__ __launch_bounds__(512) void k_kpart(const u16* __restrict__ qkv, float2* __restrict__ part) {
  int bt = blockIdx.x, q = blockIdx.y, c = threadIdx.x;
  const u16* base = qkv + (size_t)(bt * 1024 + q * 128) * 1536 + 512 + c;
  float m = -1e30f, z = 0.f;
  #pragma unroll 4
  for (int n = 0; n < 128; ++n) {
    float v = b2f(base[(size_t)n * 1536]);
    float nm = fmaxf(m, v);
    z = z * __expf(m - nm) + __expf(v - nm);
    m = nm;
  }
  part[(size_t)(bt * 8 + q) * 512 + c] = make_float2(m, z);
}
__global__ __launch_bounds__(512) void k_kred(const float2* __restrict__ part, float2* __restrict__ kst) {
  int bt = blockIdx.x, c = threadIdx.x;
  float2 p[8];
  #pragma unroll
  for (int q = 0; q < 8; ++q) p[q] = part[(size_t)(bt * 8 + q) * 512 + c];
  float M = p[0].x;
  #pragma unroll
  for (int q = 1; q < 8; ++q) M = fmaxf(M, p[q].x);
  float Z = 0.f;
  #pragma unroll
  for (int q = 0; q < 8; ++q) Z += p[q].y * __expf(p[q].x - M);
  kst[(size_t)bt * 512 + c] = make_float2(M, 1.0f / Z);
}

// ---------------- ctx[d][e] = sum_n softmax_n(k)[d][n] * v[e][n] ; writes ctxT[e][d] bf16 ----------------
__global__ __launch_bounds__(256) void k_ctx(const u16* __restrict__ qkv, const float2* __restrict__ kst,
                                             u16* __restrict__ ctxT) {
  __shared__ u16 Kc[64 * 64];
  __shared__ u16 Vc[64 * 64];
  __shared__ float Ek[64 * 64];
  __shared__ float Ms[64], Zs[64];
  int bh = blockIdx.x; int bt = bh >> 3, h = bh & 7;
  int tid = threadIdx.x;
  if (tid < 64) { float2 mz = kst[(size_t)bh * 64 + tid]; Ms[tid] = mz.x; Zs[tid] = mz.y; }
  int td = tid & 15, te = tid >> 4;
  int d0 = td * 4, e0 = te * 4;
  float acc[4][4] = {};
  int r = tid >> 2, part = tid & 3;
  int colbase = (part < 2) ? (512 + h * 64 + part * 32) : (1024 + h * 64 + (part - 2) * 32);
  u16* ldst = (part < 2) ? &Kc[r * 64 + part * 32] : &Vc[r * 64 + (part - 2) * 32];
  for (int ch = 0; ch < 16; ++ch) {
    __syncthreads();
    int n0 = ch * 64;
    const uint4* src = (const uint4*)(qkv + (size_t)(bt * 1024 + n0 + r) * 1536 + colbase);
    uint4* dst = (uint4*)ldst;
    #pragma unroll
    for (int i = 0; i < 4; ++i) dst[i] = src[i];
    __syncthreads();
    {
      int nn = tid >> 2, dbase = (tid & 3) * 16;
      #pragma unroll
      for (int ii = 0; ii < 16; ++ii) {
        int d = dbase + ii;
        Ek[nn * 64 + d] = __expf(b2f(Kc[nn * 64 + d]) - Ms[d]) * Zs[d];
      }
    }
    __syncthreads();
    #pragma unroll 2
    for (int n = 0; n < 64; ++n) {
      float4 ek = *(const float4*)&Ek[n * 64 + d0];
      float ekf[4] = {ek.x, ek.y, ek.z, ek.w};
      ushort4 vv = *(const ushort4*)&Vc[n * 64 + e0];
      float vf[4] = {b2f(vv.x), b2f(vv.y), b2f(vv.z), b2f(vv.w)};
      #pragma unroll
      for (int i = 0; i < 4; ++i)
        #pragma unroll
        for (int j = 0; j < 4; ++j)
          acc[i][j] += ekf[i] * vf[j];
    }
  }
  #pragma unroll
  for (int j = 0; j < 4; ++j)
    #pragma unroll
    for (int i = 0; i < 4; ++i)
      ctxT[(size_t)bh * 4096 + (e0 + j) * 64 + d0 + i] = f2b(acc[i][j]);
}

// ---------------- out1T[row][h*64+e] = sum_d qs[row][h*64+d] * ctx[d][e]  (MFMA) ----------------
__global__ __launch_bounds__(256) void k_apply(const u16* __restrict__ qkv, const u16* __restrict__ ctxT,
                                               u16* __restrict__ out1) {
  __shared__ u16 ct[64 * 72]; // ctxT[e][d], padded stride 72
  int bh = blockIdx.x; int bt = bh >> 3, h = bh & 7;
  int tid = threadIdx.x; int w = tid >> 6, lane = tid & 63;
  {
    int e = tid >> 2, db = (tid & 3) * 16;
    const uint4* s = (const uint4*)&ctxT[(size_t)bh * 4096 + e * 64 + db];
    *(uint4*)&ct[e * 72 + db] = s[0];
    *(uint4*)&ct[e * 72 + db + 8] = s[1];
  }
  __syncthreads();
  int fr = lane & 15, fq = lane >> 4;
  short8 bfrag[4][2];
  #pragma unroll
  for (int n = 0; n < 4; ++n)
    #pragma unroll
    for (int ks = 0; ks < 2; ++ks)
      bfrag[n][ks] = *(const short8*)&ct[(n * 16 + fr) * 72 + ks * 32 + fq * 8];
  const u16* qbase = qkv + (size_t)(bt * 1024 + w * 256) * 1536 + h * 64;
  for (int mt = 0; mt < 16; ++mt) {
    f32x4 acc[4] = {};
    short8 af[2];
    #pragma unroll
    for (int ks = 0; ks < 2; ++ks)
      af[ks] = *(const short8*)(qbase + (size_t)(mt * 16 + fr) * 1536 + ks * 32 + fq * 8);
    #pragma unroll
    for (int ks = 0; ks < 2; ++ks)
      #pragma unroll
      for (int n = 0; n < 4; ++n)
        acc[n] = __builtin_amdgcn_mfma_f32_16x16x32_bf16(af[ks], bfrag[n][ks], acc[n], 0, 0, 0);
    #pragma unroll
    for (int n = 0; n < 4; ++n) {
      #pragma unroll
      for (int r2 = 0; r2 < 4; ++r2) {
        int row = bt * 1024 + w * 256 + mt * 16 + fq * 4 + r2;
        out1[(size_t)row * 512 + h * 64 + n * 16 + fr] = f2b(acc[n][r2]);
      }
    }
  }
}

// ---------------- temporal attention: per (b,s): 8 heads, 16x16 attn over t, d=64 ----------------
__global__ __launch_bounds__(128) void k_tattn(const u16* __restrict__ qkvt, u16* __restrict__ outbuf) {
  __shared__ u16 L[16 * 1536];
  int bs = blockIdx.x;
  int b = bs >> 10, s = bs & 1023;
  int tid = threadIdx.x;
  {
    int row = tid >> 3, seg = tid & 7;
    const uint4* src = (const uint4*)(qkvt + ((size_t)((b * 16 + row) * 1024 + s)) * 1536 + seg * 192);
    uint4* dst = (uint4*)(L + row * 1536 + seg * 192);
    #pragma unroll
    for (int i = 0; i < 24; ++i) dst[i] = src[i];
  }
  __syncthreads();
  int h = tid >> 4, i = tid & 15;
  const u16* qrow = L + i * 1536 + h * 64;
  float qf[64];
  #pragma unroll
  for (int c = 0; c < 16; ++c) {
    ushort4 u = *(const ushort4*)(qrow + c * 4);
    qf[c*4+0] = b2f(u.x); qf[c*4+1] = b2f(u.y); qf[c*4+2] = b2f(u.z); qf[c*4+3] = b2f(u.w);
  }
  float sim[16];
  #pragma unroll 1
  for (int j = 0; j < 16; ++j) {
    const u16* krow = L + j * 1536 + 512 + h * 64;
    float acc = 0.f;
    #pragma unroll
    for (int c = 0; c < 16; ++c) {
      ushort4 u = *(const ushort4*)(krow + c * 4);
      acc += qf[c*4+0]*b2f(u.x) + qf[c*4+1]*b2f(u.y) + qf[c*4+2]*b2f(u.z) + qf[c*4+3]*b2f(u.w);
    }
    sim[j] = acc * 0.125f;
  }
  float mx = sim[0];
  #pragma unroll
  for (int j = 1; j < 16; ++j) mx = fmaxf(mx, sim[j]);
  float ssum = 0.f;
  #pragma unroll
  for (int j = 0; j < 16; ++j) { sim[j] = __expf(sim[j] - mx); ssum += sim[j]; }
  float inv = 1.0f / ssum;
  float outv[64];
  #pragma unroll
  for (int d = 0; d < 64; ++d) outv[d] = 0.f;
  #pragma unroll 1
  for (int j = 0; j < 16; ++j) {
    float a = sim[j] * inv;
    const u16* vrow = L + j * 1536 + 1024 + h * 64;
    #pragma unroll
    for (int c = 0; c < 16; ++c) {
      ushort4 u = *(const ushort4*)(vrow + c * 4);
      outv[c*4+0] += a * b2f(u.x); outv[c*4+1] += a * b2f(u.y);
      outv[c*4+2] += a * b2f(u.z); outv[c*4+3] += a * b2f(u.w);
    }
  }
  u16* dst = outbuf + ((size_t)((b * 16 + i) * 1024 + s)) * 512 + h * 64;
  #pragma unroll
  for (int c = 0; c < 8; ++c) {
    uint4 o = make_uint4(pack2(outv[c*8+0], outv[c*8+1]), pack2(outv[c*8+2], outv[c*8+3]),
                         pack2(outv[c*8+4], outv[c*8+5]), pack2(outv[c*8+6], outv[c*8+7]));
    ((uint4*)dst)[c] = o;
  }
}

// ---------------- final: out(b,c,t,n) = x + transpose(h2T) ----------------
__global__ __launch_bounds__(256) void k_final(const float* __restrict__ x, const u16* __restrict__ h2T,
                                               float* __restrict__ out) {
  __shared__ u16 tile[64 * 65]; // [c][n]
  int bt = blockIdx.x, c0 = blockIdx.y * 64, n0 = blockIdx.z * 64;
  int b = bt >> 4, t = bt & 15;
  int tid = threadIdx.x;
  {
    int nl = tid >> 2, cs = (tid & 3) * 16;
    const u16* src = h2T + (size_t)(bt * 1024 + n0 + nl) * 512 + c0 + cs;
    uint4 a = ((const uint4*)src)[0], bb = ((const uint4*)src)[1];
    u32 uu[8] = {a.x, a.y, a.z, a.w, bb.x, bb.y, bb.z, bb.w};
    #pragma unroll
    for (int j = 0; j < 8; ++j) {
      tile[(cs + j * 2) * 65 + nl]     = (u16)(uu[j] & 0xffffu);
      tile[(cs + j * 2 + 1) * 65 + nl] = (u16)(uu[j] >> 16);
    }
  }
  __syncthreads();
  const size_t xoff = ((size_t)(b * 512 + c0) * 16 + t) * 1024 + n0;
  #pragma unroll
  for (int it = 0; it < 16; ++it) {
    int cl = it * 4 + (tid >> 6), nl = tid & 63;
    size_t o = xoff + (size_t)cl * 16384 + nl;
    out[o] = x[o] + b2f(tile[cl * 65 + nl]);
  }
}

extern "C" void kernel_launch(void* const* d_in, const int* in_sizes, int n_in,
                              void* d_out, int out_size, void* d_ws, size_t ws_size,
                              hipStream_t stream) {
  const float* x      = (const float*)d_in[0];
  const float* w_sqkv = (const float*)d_in[1];
  const float* w_sout = (const float*)d_in[2];
  const float* b_sout = (const float*)d_in[3];
  const float* w_tqkv = (const float*)d_in[4];
  const float* w_tout = (const float*)d_in[5];
  float* out = (float*)d_out;
  char* ws = (char*)d_ws;

  u16* wsqkv_b = (u16*)(ws + OFF_WSQKV);
  u16* wsout_b = (u16*)(ws + OFF_WSOUT);
  u16* wtqkv_b = (u16*)(ws + OFF_WTQKV);
  u16* wtout_b = (u16*)(ws + OFF_WTOUT);
  float2* kst  = (float2*)(ws + OFF_KST);
  u16* ctxT    = (u16*)(ws + OFF_CTXT);
  u16* xT      = (u16*)(ws + OFF_XT);   // later reused as h2T
  u16* qkv     = (u16*)(ws + OFF_QKV);  // spatial qkv, later temporal qkv
  u16* mid     = (u16*)(ws + OFF_MID);  // out1T, later attout
  u16* midB    = (u16*)(ws + OFF_MIDB); // h1T
  float2* part = (float2*)(ws + OFF_PART);

  k_cvtw<<<3072, 256, 0, stream>>>(w_sqkv, w_sout, w_tqkv, w_tout, wsqkv_b, wsout_b, wtqkv_b, wtout_b);
  k_xT<<<dim3(32, 8, 16), 256, 0, stream>>>(x, xT);
  gemm8<1536, 0><<<dim3(128, 6), 512, 0, stream>>>(xT, wsqkv_b, nullptr, qkv);
  k_qsoft<<<1024, 256, 0, stream>>>(qkv);
  k_kpart<<<dim3(32, 8), 512, 0, stream>>>(qkv, part);
  k_kred<<<32, 512, 0, stream>>>(part, kst);
  k_ctx<<<256, 256, 0, stream>>>(qkv, kst, ctxT);
  k_apply<<<256, 256, 0, stream>>>(qkv, ctxT, mid);
  gemm8<512, 1><<<dim3(128, 2), 512, 0, stream>>>(mid, wsout_b, b_sout, midB);
  gemm8<1536, 0><<<dim3(128, 6), 512, 0, stream>>>(midB, wtqkv_b, nullptr, qkv);
  k_tattn<<<2048, 128, 0, stream>>>(qkv, mid);
  gemm8<512, 0><<<dim3(128, 2), 512, 0, stream>>>(mid, wtout_b, nullptr, xT);
  k_final<<<dim3(32, 8, 16), 256, 0, stream>>>(x, xT, out);
}

// Round 4
// 447.623 us; speedup vs baseline: 1.4553x; 1.1179x over previous
//
#include <hip/hip_runtime.h>

typedef unsigned short u16;
typedef unsigned int   u32;
typedef __attribute__((ext_vector_type(8))) short short8;
typedef __attribute__((ext_vector_type(4))) float f32x4;

__device__ __forceinline__ u16 f2b(float f) {
  u32 u = __float_as_uint(f);
  return (u16)((u + 0x7FFFu + ((u >> 16) & 1u)) >> 16);
}
__device__ __forceinline__ float b2f(u16 b) { return __uint_as_float((u32)b << 16); }
__device__ __forceinline__ u32 pack2(float a, float b) {
  return (u32)f2b(a) | ((u32)f2b(b) << 16);
}

#define GLDS16(gp, lp) __builtin_amdgcn_global_load_lds( \
    (const __attribute__((address_space(1))) u32*)(gp), \
    (__attribute__((address_space(3))) u32*)(lp), 16, 0, 0)

// ---------------- dims ----------------
// b=2 c=512 t=16 h=32 w=32 ; BT=32 N=1024 ROWS=32768 heads=8 d=64

// ---------------- ws offsets (bytes) ----------------
#define OFF_WSQKV 0UL
#define OFF_WSOUT (OFF_WSQKV + 1536UL*512*2)
#define OFF_WTQKV (OFF_WSOUT + 512UL*512*2)
#define OFF_WTOUT (OFF_WTQKV + 1536UL*512*2)
#define OFF_KST   (OFF_WTOUT + 512UL*512*2)
#define OFF_CTXT  (OFF_KST   + 256UL*64*8)
#define OFF_XT    (OFF_CTXT  + 256UL*64*64*2)
#define OFF_QKV   (OFF_XT    + 32768UL*512*2)
#define OFF_MID   (OFF_QKV   + 32768UL*1536*2)
#define OFF_MIDB  (OFF_MID   + 32768UL*512*2)
#define OFF_PART  (OFF_MIDB  + 32768UL*512*2)
// ctx partials (16MB f32) alias the xT region: xT is dead between gemm1 and gemm4.

// ---------------- weight f32 -> bf16 ----------------
__global__ __launch_bounds__(256) void k_cvtw(const float* ws, const float* wso,
                                              const float* wt, const float* wto,
                                              u16* o1, u16* o2, u16* o3, u16* o4) {
  int i = blockIdx.x * 256 + threadIdx.x;
  if (i < 786432) { o1[i] = f2b(ws[i]); o3[i] = f2b(wt[i]); }
  if (i < 262144) { o2[i] = f2b(wso[i]); o4[i] = f2b(wto[i]); }
}

// ---------------- x (b,c,t,n) f32 -> xT [bt*N+n][c] bf16 ----------------
__global__ __launch_bounds__(256) void k_xT(const float* __restrict__ x, u16* __restrict__ xT) {
  __shared__ u16 tile[64 * 65]; // [c][n]
  int bt = blockIdx.x, c0 = blockIdx.y * 64, n0 = blockIdx.z * 64;
  int b = bt >> 4, t = bt & 15;
  int tid = threadIdx.x;
  const size_t xoff = ((size_t)(b * 512 + c0) * 16 + t) * 1024 + n0;
  #pragma unroll
  for (int it = 0; it < 16; ++it) {
    int cl = it * 4 + (tid >> 6), nl = tid & 63;
    tile[cl * 65 + nl] = f2b(x[xoff + (size_t)cl * 16384 + nl]);
  }
  __syncthreads();
  int nl = tid >> 2, cs = (tid & 3) * 16;
  u32 uu[8];
  #pragma unroll
  for (int j = 0; j < 8; ++j) {
    u32 lo = tile[(cs + j * 2) * 65 + nl];
    u32 hi = tile[(cs + j * 2 + 1) * 65 + nl];
    uu[j] = lo | (hi << 16);
  }
  u16* dst = xT + (size_t)(bt * 1024 + n0 + nl) * 512 + c0 + cs;
  ((uint4*)dst)[0] = make_uint4(uu[0], uu[1], uu[2], uu[3]);
  ((uint4*)dst)[1] = make_uint4(uu[4], uu[5], uu[6], uu[7]);
}

// ---------------- 8-phase 256x256 GEMM: C[row][o] = sum_c A[row][c]*B[o][c] (+bias) ----------------
// QSOFT: blocks with bn<2 (q-part cols) apply per-(row,head) softmax over 64 channels * 0.125
// before the bf16 store (wave strip = exactly one head; channels live across the 16 fr-lanes
// of one fq group -> shfl_xor reduce).
template <int NOUT, int BIAS, int QSOFT>
__global__ __launch_bounds__(512, 2) void gemm8(const u16* __restrict__ A, const u16* __restrict__ B,
                                                const float* __restrict__ bias, u16* __restrict__ C) {
  __shared__ u16 lds[65536];
  const int tid = threadIdx.x;
  const int wid = tid >> 6, lane = tid & 63;
  const int wm = wid >> 2, wn = wid & 3;
  const int fr = lane & 15, fq = lane >> 4;
  const int bm = blockIdx.x, bn = blockIdx.y;
  const long arow0 = (long)bm * 256, brow0 = (long)bn * 256;

  const int srow  = wid * 16 + (lane >> 2);                 // row 0..127 within load chunk
  const int scol8 = ((lane & 3) ^ ((lane >> 3) & 3)) * 8;   // pre-swizzled col element within 32-col half
  const int rslot = (fq ^ ((fr >> 1) & 3)) * 8;             // swizzled read slot (u16 units)

  auto stage = [&](int mat, int bfi, int s, int kt) {
    const u16* src = (mat == 0 ? A + (arow0 + srow) * 512 : B + (brow0 + srow) * 512)
                     + kt * 64 + s * 32 + scol8;
    int off = ((bfi * 2 + mat) * 2 + s) * 8192 + wid * 512;
    GLDS16(src, &lds[off]);
    GLDS16(src + 128 * 512, &lds[off + 4096]);
  };
  auto ldA = [&](int bfi, int s, int m) -> short8 {
    int row = wm * 128 + m * 16 + fr;
    return *(const short8*)&lds[((bfi * 2 + 0) * 2 + s) * 8192 + row * 32 + rslot];
  };
  auto ldB = [&](int bfi, int s, int n) -> short8 {
    int row = wn * 64 + n * 16 + fr;
    return *(const short8*)&lds[((bfi * 2 + 1) * 2 + s) * 8192 + row * 32 + rslot];
  };

  f32x4 acc[8][4] = {};
  short8 af[8]; short8 bf0, bf1;

  // prologue: buf0 <- K-tile 0 (A-ks0, B-ks0, A-ks1, B-ks1); buf1 <- K-tile 1 (A-ks0, B-ks0, A-ks1)
  stage(0, 0, 0, 0); stage(1, 0, 0, 0); stage(0, 0, 1, 0); stage(1, 0, 1, 0);
  stage(0, 1, 0, 1); stage(1, 1, 0, 1); stage(0, 1, 1, 1);
  asm volatile("s_waitcnt vmcnt(4)" ::: "memory");
  asm volatile("" ::: "memory");
  __builtin_amdgcn_s_barrier();

#define PHASE(BUFI, S, NH, READ_A, SM, SB, SS, SKT, DO_VM)                          \
  {                                                                                 \
    if (READ_A) { _Pragma("unroll") for (int m = 0; m < 8; ++m) af[m] = ldA(BUFI, S, m); } \
    bf0 = ldB(BUFI, S, (NH)*2); bf1 = ldB(BUFI, S, (NH)*2 + 1);                     \
    stage(SM, SB, SS, SKT);                                                         \
    asm volatile("" ::: "memory");                                                  \
    __builtin_amdgcn_s_barrier();                                                   \
    asm volatile("s_waitcnt lgkmcnt(0)" ::: "memory");                              \
    __builtin_amdgcn_sched_barrier(0);                                              \
    __builtin_amdgcn_s_setprio(1);                                                  \
    _Pragma("unroll") for (int m = 0; m < 8; ++m) {                                 \
      acc[m][(NH)*2]   = __builtin_amdgcn_mfma_f32_16x16x32_bf16(af[m], bf0, acc[m][(NH)*2], 0, 0, 0);     \
      acc[m][(NH)*2+1] = __builtin_amdgcn_mfma_f32_16x16x32_bf16(af[m], bf1, acc[m][(NH)*2+1], 0, 0, 0);   \
    }                                                                               \
    __builtin_amdgcn_s_setprio(0);                                                  \
    if (DO_VM) asm volatile("s_waitcnt vmcnt(4)" ::: "memory");                     \
    asm volatile("" ::: "memory");                                                  \
    __builtin_amdgcn_s_barrier();                                                   \
  }

  for (int i = 0; i < 4; ++i) {
    const int kb = 2 * i;
    const int k1 = kb + 1;
    const int k2 = (kb + 2 < 8) ? kb + 2 : 7;
    const int k3 = (kb + 3 < 8) ? kb + 3 : 7;
    PHASE(0, 0, 0, 1, 1, 1, 1, k1, 0)  // ph1: compute buf0/ks0/n01; stage buf1.B-ks1 <- k1
    PHASE(0, 0, 1, 0, 0, 0, 0, k2, 0)  // ph2: buf0/ks0/n23; stage buf0.A-ks0 <- k2
    PHASE(0, 1, 0, 1, 1, 0, 0, k2, 0)  // ph3: buf0/ks1/n01; stage buf0.B-ks0 <- k2
    PHASE(0, 1, 1, 0, 0, 0, 1, k2, 1)  // ph4: buf0/ks1/n23; stage buf0.A-ks1 <- k2; vmcnt(4)
    PHASE(1, 0, 0, 1, 1, 0, 1, k2, 0)  // ph5: buf1/ks0/n01; stage buf0.B-ks1 <- k2
    PHASE(1, 0, 1, 0, 0, 1, 0, k3, 0)  // ph6: buf1/ks0/n23; stage buf1.A-ks0 <- k3
    PHASE(1, 1, 0, 1, 1, 1, 0, k3, 0)  // ph7: buf1/ks1/n01; stage buf1.B-ks0 <- k3
    PHASE(1, 1, 1, 0, 0, 1, 1, k3, 1)  // ph8: buf1/ks1/n23; stage buf1.A-ks1 <- k3; vmcnt(4)
  }
#undef PHASE

  if (QSOFT && bn < 2) {
    #pragma unroll
    for (int m = 0; m < 8; ++m) {
      #pragma unroll
      for (int r = 0; r < 4; ++r) {
        float a0 = acc[m][0][r], a1 = acc[m][1][r], a2 = acc[m][2][r], a3 = acc[m][3][r];
        float mx = fmaxf(fmaxf(a0, a1), fmaxf(a2, a3));
        #pragma unroll
        for (int s = 1; s < 16; s <<= 1) mx = fmaxf(mx, __shfl_xor(mx, s));
        float e0 = __expf(a0 - mx), e1 = __expf(a1 - mx), e2 = __expf(a2 - mx), e3 = __expf(a3 - mx);
        float sum = e0 + e1 + e2 + e3;
        #pragma unroll
        for (int s = 1; s < 16; s <<= 1) sum += __shfl_xor(sum, s);
        float sc = 0.125f / sum;
        acc[m][0][r] = e0 * sc; acc[m][1][r] = e1 * sc;
        acc[m][2][r] = e2 * sc; acc[m][3][r] = e3 * sc;
      }
    }
  }

  #pragma unroll
  for (int m = 0; m < 8; ++m) {
    long row = arow0 + wm * 128 + m * 16 + fq * 4;
    #pragma unroll
    for (int n = 0; n < 4; ++n) {
      long col = brow0 + wn * 64 + n * 16 + fr;
      float bv = BIAS ? bias[col] : 0.0f;
      u16* cp = C + (size_t)row * NOUT + col;
      #pragma unroll
      for (int r = 0; r < 4; ++r)
        cp[(size_t)r * NOUT] = f2b(acc[m][n][r] + bv);
    }
  }
}

// ---------------- spatial k stats: online per-column max/sumexp, coalesced ----------------
__global__ __launch_bounds__(512) void k_kpart(const u16* __restrict__ qkv, float2* __restrict__ part) {
  int bt = blockIdx.x, q = blockIdx.y, c = threadIdx.x;
  const u16* base = qkv + (size_t)(bt * 1024 + q * 128) * 1536 + 512 + c;
  float m = -1e30f, z = 0.f;
  #pragma unroll 4
  for (int n = 0; n < 128; ++n) {
    float v = b2f(base[(size_t)n * 1536]);
    float nm = fmaxf(m, v);
    z = z * __expf(m - nm) + __expf(v - nm);
    m = nm;
  }
  part[(size_t)(bt * 8 + q) * 512 + c] = make_float2(m, z);
}
__global__ __launch_bounds__(512) void k_kred(const float2* __restrict__ part, float2* __restrict__ kst) {
  int bt = blockIdx.x, c = threadIdx.x;
  float2 p[8];
  #pragma unroll
  for (int q = 0; q < 8; ++q) p[q] = part[(size_t)(bt * 8 + q) * 512 + c];
  float M = p[0].x;
  #pragma unroll
  for (int q = 1; q < 8; ++q) M = fmaxf(M, p[q].x);
  float Z = 0.f;
  #pragma unroll
  for (int q = 0; q < 8; ++q) Z += p[q].y * __expf(p[q].x - M);
  kst[(size_t)bt * 512 + c] = make_float2(M, 1.0f / Z);
}

// ---------------- ctx partials via MFMA ----------------
// grid (bt=32, h=8, nc=4); block 256 (4 waves). Each block: n in [nc*256, nc*256+256).
// ctxp[((bt*8+h)*4+nc)*4096 + e*64 + d] = invZ[d] * sum_n exp(K[d][n]-M[d]) * V[e][n]
__global__ __launch_bounds__(256) void k_ctx(const u16* __restrict__ qkv, const float2* __restrict__ kst,
                                             float* __restrict__ ctxp) {
  __shared__ u16 Lraw[64 * 128];   // [n][c]: c 0-63 = K cols, 64-127 = V cols
  __shared__ u16 ET[128 * 64];     // [row][n], XOR-swizzled 16B slots; rows 0-63 Ek(d), 64-127 V(e)
  __shared__ float Ms[64], Zs[64];
  const int bt = blockIdx.x, h = blockIdx.y, nc = blockIdx.z;
  const int tid = threadIdx.x;
  const int wv = tid >> 6, lane = tid & 63;
  const int fr = lane & 15, fq = lane >> 4;
  if (tid < 64) { float2 mz = kst[(size_t)bt * 512 + h * 64 + tid]; Ms[tid] = mz.x; Zs[tid] = mz.y; }

  // staging lane mapping: 16B segment per lane; 4 rows per GLDS16 call
  const int ci = lane & 15;
  const long gcol = (ci < 8) ? (512 + h * 64 + ci * 8) : (1024 + h * 64 + (ci - 8) * 8);
  const long grow0 = (long)bt * 1024 + nc * 256;
  auto stage = [&](int sc) {
    #pragma unroll
    for (int j = 0; j < 4; ++j) {
      int nl = wv * 16 + j * 4 + (lane >> 4);
      const u16* src = qkv + (grow0 + sc * 64 + nl) * 1536 + gcol;
      GLDS16(src, &Lraw[(wv * 16 + j * 4) * 128]);
    }
  };

  // transpose mapping: wave-uniform K/V split
  const int half = tid >> 7;          // 0: K cols, 1: V cols
  const int cpl  = tid & 31;          // col pair
  const int rg   = (tid >> 5) & 3;    // row group (16 n)
  const int c0   = half * 64 + cpl * 2, c1 = c0 + 1;
  const int sw   = (fr >> 1) & 7;     // frag-read slot swizzle

  f32x4 acc[4] = {};
  stage(0);
  for (int sc = 0; sc < 4; ++sc) {
    asm volatile("s_waitcnt vmcnt(0)" ::: "memory");
    __syncthreads();
    // ---- transpose + exp: Lraw[n][c] -> ET[c][n] ----
    {
      u32 w[16];
      #pragma unroll
      for (int j = 0; j < 16; ++j)
        w[j] = *(const u32*)&Lraw[(rg * 16 + j) * 128 + c0];
      u16 o0[16], o1[16];
      if (half == 0) {
        float M0 = Ms[c0], M1 = Ms[c1];
        #pragma unroll
        for (int j = 0; j < 16; ++j) {
          o0[j] = f2b(__expf(__uint_as_float(w[j] << 16) - M0));
          o1[j] = f2b(__expf(__uint_as_float(w[j] & 0xffff0000u) - M1));
        }
      } else {
        #pragma unroll
        for (int j = 0; j < 16; ++j) { o0[j] = (u16)(w[j] & 0xffffu); o1[j] = (u16)(w[j] >> 16); }
      }
      #pragma unroll
      for (int s2 = 0; s2 < 2; ++s2) {
        int phys = (rg * 2 + s2) ^ (cpl & 7);
        uint4 p0 = make_uint4(
            (u32)o0[s2*8+0] | ((u32)o0[s2*8+1] << 16), (u32)o0[s2*8+2] | ((u32)o0[s2*8+3] << 16),
            (u32)o0[s2*8+4] | ((u32)o0[s2*8+5] << 16), (u32)o0[s2*8+6] | ((u32)o0[s2*8+7] << 16));
        uint4 p1 = make_uint4(
            (u32)o1[s2*8+0] | ((u32)o1[s2*8+1] << 16), (u32)o1[s2*8+2] | ((u32)o1[s2*8+3] << 16),
            (u32)o1[s2*8+4] | ((u32)o1[s2*8+5] << 16), (u32)o1[s2*8+6] | ((u32)o1[s2*8+7] << 16));
        *(uint4*)&ET[c0 * 64 + phys * 8] = p0;
        *(uint4*)&ET[c1 * 64 + phys * 8] = p1;
      }
    }
    __syncthreads();
    if (sc < 3) stage(sc + 1);
    // ---- MFMA: wave wv computes d-strip [wv*16, +16) x e[0,64) ----
    {
      short8 afr[2];
      #pragma unroll
      for (int ks = 0; ks < 2; ++ks) {
        int row = wv * 16 + fr;
        afr[ks] = *(const short8*)&ET[row * 64 + ((ks * 4 + fq) ^ sw) * 8];
      }
      #pragma unroll
      for (int nt = 0; nt < 4; ++nt) {
        int row = 64 + nt * 16 + fr;
        #pragma unroll
        for (int ks = 0; ks < 2; ++ks) {
          short8 bfr = *(const short8*)&ET[row * 64 + ((ks * 4 + fq) ^ sw) * 8];
          acc[nt] = __builtin_amdgcn_mfma_f32_16x16x32_bf16(afr[ks], bfr, acc[nt], 0, 0, 0);
        }
      }
    }
    __syncthreads();
  }
  // epilogue: d = wv*16 + fq*4 + r ; e = nt*16 + fr ; apply invZ[d]; store f32 partial [e][d]
  float iz0 = Zs[wv * 16 + fq * 4 + 0], iz1 = Zs[wv * 16 + fq * 4 + 1];
  float iz2 = Zs[wv * 16 + fq * 4 + 2], iz3 = Zs[wv * 16 + fq * 4 + 3];
  size_t cbase = ((size_t)((bt * 8 + h) * 4 + nc)) * 4096;
  #pragma unroll
  for (int nt = 0; nt < 4; ++nt) {
    f32x4 v = acc[nt];
    v[0] *= iz0; v[1] *= iz1; v[2] *= iz2; v[3] *= iz3;
    *(f32x4*)&ctxp[cbase + (size_t)(nt * 16 + fr) * 64 + wv * 16 + fq * 4] = v;
  }
}

// ---------------- out1T[row][h*64+e] = sum_d qs[row][h*64+d] * ctx[d][e]  (MFMA) ----------------
__global__ __launch_bounds__(256) void k_apply(const u16* __restrict__ qkv, const float* __restrict__ ctxp,
                                               u16* __restrict__ out1) {
  __shared__ u16 ct[64 * 72]; // ct[e][d], padded stride 72
  int bh = blockIdx.x; int bt = bh >> 3, h = bh & 7;
  int tid = threadIdx.x; int w = tid >> 6, lane = tid & 63;
  {
    int e = tid >> 2, db = (tid & 3) * 16;
    float s[16] = {};
    size_t pbase = (size_t)bh * 4 * 4096 + (size_t)e * 64 + db;
    #pragma unroll
    for (int ncp = 0; ncp < 4; ++ncp) {
      const float4* p = (const float4*)&ctxp[pbase + (size_t)ncp * 4096];
      #pragma unroll
      for (int j = 0; j < 4; ++j) {
        float4 v = p[j];
        s[j*4+0] += v.x; s[j*4+1] += v.y; s[j*4+2] += v.z; s[j*4+3] += v.w;
      }
    }
    u32 pk[8];
    #pragma unroll
    for (int j = 0; j < 8; ++j) pk[j] = pack2(s[2*j], s[2*j+1]);
    *(uint4*)&ct[e * 72 + db]     = make_uint4(pk[0], pk[1], pk[2], pk[3]);
    *(uint4*)&ct[e * 72 + db + 8] = make_uint4(pk[4], pk[5], pk[6], pk[7]);
  }
  __syncthreads();
  int fr = lane & 15, fq = lane >> 4;
  short8 bfrag[4][2];
  #pragma unroll
  for (int n = 0; n < 4; ++n)
    #pragma unroll
    for (int ks = 0; ks < 2; ++ks)
      bfrag[n][ks] = *(const short8*)&ct[(n * 16 + fr) * 72 + ks * 32 + fq * 8];
  const u16* qbase = qkv + (size_t)(bt * 1024 + w * 256) * 1536 + h * 64;
  for (int mt = 0; mt < 16; ++mt) {
    f32x4 acc[4] = {};
    short8 af[2];
    #pragma unroll
    for (int ks = 0; ks < 2; ++ks)
      af[ks] = *(const short8*)(qbase + (size_t)(mt * 16 + fr) * 1536 + ks * 32 + fq * 8);
    #pragma unroll
    for (int ks = 0; ks < 2; ++ks)
      #pragma unroll
      for (int n = 0; n < 4; ++n)
        acc[n] = __builtin_amdgcn_mfma_f32_16x16x32_bf16(af[ks], bfrag[n][ks], acc[n], 0, 0, 0);
    #pragma unroll
    for (int n = 0; n < 4; ++n) {
      #pragma unroll
      for (int r2 = 0; r2 < 4; ++r2) {
        int row = bt * 1024 + w * 256 + mt * 16 + fq * 4 + r2;
        out1[(size_t)row * 512 + h * 64 + n * 16 + fr] = f2b(acc[n][r2]);
      }
    }
  }
}

// ---------------- temporal attention: per (b,s): 8 heads, 16x16 attn over t, d=64 ----------------
__global__ __launch_bounds__(128) void k_tattn(const u16* __restrict__ qkvt, u16* __restrict__ outbuf) {
  __shared__ u16 L[16 * 1536];
  int bs = blockIdx.x;
  int b = bs >> 10, s = bs & 1023;
  int tid = threadIdx.x;
  {
    int row = tid >> 3, seg = tid & 7;
    const uint4* src = (const uint4*)(qkvt + ((size_t)((b * 16 + row) * 1024 + s)) * 1536 + seg * 192);
    uint4* dst = (uint4*)(L + row * 1536 + seg * 192);
    #pragma unroll
    for (int i = 0; i < 24; ++i) dst[i] = src[i];
  }
  __syncthreads();
  int h = tid >> 4, i = tid & 15;
  const u16* qrow = L + i * 1536 + h * 64;
  float qf[64];
  #pragma unroll
  for (int c = 0; c < 16; ++c) {
    ushort4 u = *(const ushort4*)(qrow + c * 4);
    qf[c*4+0] = b2f(u.x); qf[c*4+1] = b2f(u.y); qf[c*4+2] = b2f(u.z); qf[c*4+3] = b2f(u.w);
  }
  float sim[16];
  #pragma unroll 1
  for (int j = 0; j < 16; ++j) {
    const u16* krow = L + j * 1536 + 512 + h * 64;
    float acc = 0.f;
    #pragma unroll
    for (int c = 0; c < 16; ++c) {
      ushort4 u = *(const ushort4*)(krow + c * 4);
      acc += qf[c*4+0]*b2f(u.x) + qf[c*4+1]*b2f(u.y) + qf[c*4+2]*b2f(u.z) + qf[c*4+3]*b2f(u.w);
    }
    sim[j] = acc * 0.125f;
  }
  float mx = sim[0];
  #pragma unroll
  for (int j = 1; j < 16; ++j) mx = fmaxf(mx, sim[j]);
  float ssum = 0.f;
  #pragma unroll
  for (int j = 0; j < 16; ++j) { sim[j] = __expf(sim[j] - mx); ssum += sim[j]; }
  float inv = 1.0f / ssum;
  float outv[64];
  #pragma unroll
  for (int d = 0; d < 64; ++d) outv[d] = 0.f;
  #pragma unroll 1
  for (int j = 0; j < 16; ++j) {
    float a = sim[j] * inv;
    const u16* vrow = L + j * 1536 + 1024 + h * 64;
    #pragma unroll
    for (int c = 0; c < 16; ++c) {
      ushort4 u = *(const ushort4*)(vrow + c * 4);
      outv[c*4+0] += a * b2f(u.x); outv[c*4+1] += a * b2f(u.y);
      outv[c*4+2] += a * b2f(u.z); outv[c*4+3] += a * b2f(u.w);
    }
  }
  u16* dst = outbuf + ((size_t)((b * 16 + i) * 1024 + s)) * 512 + h * 64;
  #pragma unroll
  for (int c = 0; c < 8; ++c) {
    uint4 o = make_uint4(pack2(outv[c*8+0], outv[c*8+1]), pack2(outv[c*8+2], outv[c*8+3]),
                         pack2(outv[c*8+4], outv[c*8+5]), pack2(outv[c*8+6], outv[c*8+7]));
    ((uint4*)dst)[c] = o;
  }
}

// ---------------- final: out(b,c,t,n) = x + transpose(h2T) ----------------
__global__ __launch_bounds__(256) void k_final(const float* __restrict__ x, const u16* __restrict__ h2T,
                                               float* __restrict__ out) {
  __shared__ u16 tile[64 * 65]; // [c][n]
  int bt = blockIdx.x, c0 = blockIdx.y * 64, n0 = blockIdx.z * 64;
  int b = bt >> 4, t = bt & 15;
  int tid = threadIdx.x;
  {
    int nl = tid >> 2, cs = (tid & 3) * 16;
    const u16* src = h2T + (size_t)(bt * 1024 + n0 + nl) * 512 + c0 + cs;
    uint4 a = ((const uint4*)src)[0], bb = ((const uint4*)src)[1];
    u32 uu[8] = {a.x, a.y, a.z, a.w, bb.x, bb.y, bb.z, bb.w};
    #pragma unroll
    for (int j = 0; j < 8; ++j) {
      tile[(cs + j * 2) * 65 + nl]     = (u16)(uu[j] & 0xffffu);
      tile[(cs + j * 2 + 1) * 65 + nl] = (u16)(uu[j] >> 16);
    }
  }
  __syncthreads();
  const size_t xoff = ((size_t)(b * 512 + c0) * 16 + t) * 1024 + n0;
  #pragma unroll
  for (int it = 0; it < 16; ++it) {
    int cl = it * 4 + (tid >> 6), nl = tid & 63;
    size_t o = xoff + (size_t)cl * 16384 + nl;
    out[o] = x[o] + b2f(tile[cl * 65 + nl]);
  }
}

extern "C" void kernel_launch(void* const* d_in, const int* in_sizes, int n_in,
                              void* d_out, int out_size, void* d_ws, size_t ws_size,
                              hipStream_t stream) {
  const float* x      = (const float*)d_in[0];
  const float* w_sqkv = (const float*)d_in[1];
  const float* w_sout = (const float*)d_in[2];
  const float* b_sout = (const float*)d_in[3];
  const float* w_tqkv = (const float*)d_in[4];
  const float* w_tout = (const float*)d_in[5];
  float* out = (float*)d_out;
  char* ws = (char*)d_ws;

  u16* wsqkv_b = (u16*)(ws + OFF_WSQKV);
  u16* wsout_b = (u16*)(ws + OFF_WSOUT);
  u16* wtqkv_b = (u16*)(ws + OFF_WTQKV);
  u16* wtout_b = (u16*)(ws + OFF_WTOUT);
  float2* kst  = (float2*)(ws + OFF_KST);
  u16* xT      = (u16*)(ws + OFF_XT);   // later reused as h2T
  float* ctxp  = (float*)(ws + OFF_XT); // aliases xT: dead between gemm1 and gemm4
  u16* qkv     = (u16*)(ws + OFF_QKV);  // spatial qkv, later temporal qkv
  u16* mid     = (u16*)(ws + OFF_MID);  // out1T, later attout
  u16* midB    = (u16*)(ws + OFF_MIDB); // h1T
  float2* part = (float2*)(ws + OFF_PART);

  k_cvtw<<<3072, 256, 0, stream>>>(w_sqkv, w_sout, w_tqkv, w_tout, wsqkv_b, wsout_b, wtqkv_b, wtout_b);
  k_xT<<<dim3(32, 8, 16), 256, 0, stream>>>(x, xT);
  gemm8<1536, 0, 1><<<dim3(128, 6), 512, 0, stream>>>(xT, wsqkv_b, nullptr, qkv);
  k_kpart<<<dim3(32, 8), 512, 0, stream>>>(qkv, part);
  k_kred<<<32, 512, 0, stream>>>(part, kst);
  k_ctx<<<dim3(32, 8, 4), 256, 0, stream>>>(qkv, kst, ctxp);
  k_apply<<<256, 256, 0, stream>>>(qkv, ctxp, mid);
  gemm8<512, 1, 0><<<dim3(128, 2), 512, 0, stream>>>(mid, wsout_b, b_sout, midB);
  gemm8<1536, 0, 0><<<dim3(128, 6), 512, 0, stream>>>(midB, wtqkv_b, nullptr, qkv);
  k_tattn<<<2048, 128, 0, stream>>>(qkv, mid);
  gemm8<512, 0, 0><<<dim3(128, 2), 512, 0, stream>>>(mid, wtout_b, nullptr, xT);
  k_final<<<dim3(32, 8, 16), 256, 0, stream>>>(x, xT, out);
}

// Round 5
// 443.960 us; speedup vs baseline: 1.4673x; 1.0083x over previous
//
#include <hip/hip_runtime.h>

typedef unsigned short u16;
typedef unsigned int   u32;
typedef __attribute__((ext_vector_type(8))) short short8;
typedef __attribute__((ext_vector_type(4))) float f32x4;

__device__ __forceinline__ u16 f2b(float f) {
  u32 u = __float_as_uint(f);
  return (u16)((u + 0x7FFFu + ((u >> 16) & 1u)) >> 16);
}
__device__ __forceinline__ float b2f(u16 b) { return __uint_as_float((u32)b << 16); }
__device__ __forceinline__ u32 pack2(float a, float b) {
  return (u32)f2b(a) | ((u32)f2b(b) << 16);
}

#define GLDS16(gp, lp) __builtin_amdgcn_global_load_lds( \
    (const __attribute__((address_space(1))) u32*)(gp), \
    (__attribute__((address_space(3))) u32*)(lp), 16, 0, 0)

// ---------------- dims ----------------
// b=2 c=512 t=16 h=32 w=32 ; BT=32 N=1024 ROWS=32768 heads=8 d=64

// ---------------- ws offsets (bytes) ----------------
#define OFF_WSQKV 0UL
#define OFF_WSOUT (OFF_WSQKV + 1536UL*512*2)
#define OFF_WTQKV (OFF_WSOUT + 512UL*512*2)
#define OFF_WTOUT (OFF_WTQKV + 1536UL*512*2)
#define OFF_KST   (OFF_WTOUT + 512UL*512*2)
#define OFF_CTXT  (OFF_KST   + 256UL*64*8)
#define OFF_XT    (OFF_CTXT  + 256UL*64*64*2)
#define OFF_QKV   (OFF_XT    + 32768UL*512*2)
#define OFF_MID   (OFF_QKV   + 32768UL*1536*2)
#define OFF_MIDB  (OFF_MID   + 32768UL*512*2)
#define OFF_PART  (OFF_MIDB  + 32768UL*512*2)
// ctx partials (16MB f32) alias the xT region: xT is dead between gemm1 and gemm4.

// ---------------- weight f32 -> bf16 ----------------
__global__ __launch_bounds__(256) void k_cvtw(const float* ws, const float* wso,
                                              const float* wt, const float* wto,
                                              u16* o1, u16* o2, u16* o3, u16* o4) {
  int i = blockIdx.x * 256 + threadIdx.x;
  if (i < 786432) { o1[i] = f2b(ws[i]); o3[i] = f2b(wt[i]); }
  if (i < 262144) { o2[i] = f2b(wso[i]); o4[i] = f2b(wto[i]); }
}

// ---------------- x (b,c,t,n) f32 -> xT [bt*N+n][c] bf16 ----------------
__global__ __launch_bounds__(256) void k_xT(const float* __restrict__ x, u16* __restrict__ xT) {
  __shared__ u16 tile[64 * 65]; // [c][n]
  int bt = blockIdx.x, c0 = blockIdx.y * 64, n0 = blockIdx.z * 64;
  int b = bt >> 4, t = bt & 15;
  int tid = threadIdx.x;
  const size_t xoff = ((size_t)(b * 512 + c0) * 16 + t) * 1024 + n0;
  #pragma unroll
  for (int it = 0; it < 16; ++it) {
    int cl = it * 4 + (tid >> 6), nl = tid & 63;
    tile[cl * 65 + nl] = f2b(x[xoff + (size_t)cl * 16384 + nl]);
  }
  __syncthreads();
  int nl = tid >> 2, cs = (tid & 3) * 16;
  u32 uu[8];
  #pragma unroll
  for (int j = 0; j < 8; ++j) {
    u32 lo = tile[(cs + j * 2) * 65 + nl];
    u32 hi = tile[(cs + j * 2 + 1) * 65 + nl];
    uu[j] = lo | (hi << 16);
  }
  u16* dst = xT + (size_t)(bt * 1024 + n0 + nl) * 512 + c0 + cs;
  ((uint4*)dst)[0] = make_uint4(uu[0], uu[1], uu[2], uu[3]);
  ((uint4*)dst)[1] = make_uint4(uu[4], uu[5], uu[6], uu[7]);
}

// ---------------- 8-phase 256x256 GEMM: C[row][o] = sum_c A[row][c]*B[o][c] (+bias) ----------------
// Grid: 1-D, 128*NBN blocks. XCD-aware mapping (T1): XCD x owns bm in [x*16, x*16+16),
// bn fastest -> A panel (256KB) is re-read by NBN co-resident blocks on the SAME XCD L2
// instead of streaming from L3/HBM NBN times.
// QSOFT: blocks with bn<2 (q-part cols) apply per-(row,head) softmax over 64 channels * 0.125.
template <int NOUT, int BIAS, int QSOFT>
__global__ __launch_bounds__(512, 2) void gemm8(const u16* __restrict__ A, const u16* __restrict__ B,
                                                const float* __restrict__ bias, u16* __restrict__ C) {
  constexpr int NBN = NOUT / 256;
  __shared__ u16 lds[65536];
  const int tid = threadIdx.x;
  const int wid = tid >> 6, lane = tid & 63;
  const int wm = wid >> 2, wn = wid & 3;
  const int fr = lane & 15, fq = lane >> 4;
  // XCD-aware block swizzle (bijective: 8 XCDs x 16 bm-chunk x NBN)
  const int xcd = blockIdx.x & 7;
  const int kk_ = blockIdx.x >> 3;            // 0 .. 16*NBN-1
  const int bm = xcd * 16 + kk_ / NBN;
  const int bn = kk_ % NBN;
  const long arow0 = (long)bm * 256, brow0 = (long)bn * 256;

  const int srow  = wid * 16 + (lane >> 2);                 // row 0..127 within load chunk
  const int scol8 = ((lane & 3) ^ ((lane >> 3) & 3)) * 8;   // pre-swizzled col element within 32-col half
  const int rslot = (fq ^ ((fr >> 1) & 3)) * 8;             // swizzled read slot (u16 units)

  auto stage = [&](int mat, int bfi, int s, int kt) {
    const u16* src = (mat == 0 ? A + (arow0 + srow) * 512 : B + (brow0 + srow) * 512)
                     + kt * 64 + s * 32 + scol8;
    int off = ((bfi * 2 + mat) * 2 + s) * 8192 + wid * 512;
    GLDS16(src, &lds[off]);
    GLDS16(src + 128 * 512, &lds[off + 4096]);
  };
  auto ldA = [&](int bfi, int s, int m) -> short8 {
    int row = wm * 128 + m * 16 + fr;
    return *(const short8*)&lds[((bfi * 2 + 0) * 2 + s) * 8192 + row * 32 + rslot];
  };
  auto ldB = [&](int bfi, int s, int n) -> short8 {
    int row = wn * 64 + n * 16 + fr;
    return *(const short8*)&lds[((bfi * 2 + 1) * 2 + s) * 8192 + row * 32 + rslot];
  };

  f32x4 acc[8][4] = {};
  short8 af[8]; short8 bf0, bf1;

  // prologue: buf0 <- K-tile 0 (A-ks0, B-ks0, A-ks1, B-ks1); buf1 <- K-tile 1 (A-ks0, B-ks0, A-ks1)
  stage(0, 0, 0, 0); stage(1, 0, 0, 0); stage(0, 0, 1, 0); stage(1, 0, 1, 0);
  stage(0, 1, 0, 1); stage(1, 1, 0, 1); stage(0, 1, 1, 1);
  asm volatile("s_waitcnt vmcnt(4)" ::: "memory");
  asm volatile("" ::: "memory");
  __builtin_amdgcn_s_barrier();

#define PHASE(BUFI, S, NH, READ_A, SM, SB, SS, SKT, DO_VM)                          \
  {                                                                                 \
    if (READ_A) { _Pragma("unroll") for (int m = 0; m < 8; ++m) af[m] = ldA(BUFI, S, m); } \
    bf0 = ldB(BUFI, S, (NH)*2); bf1 = ldB(BUFI, S, (NH)*2 + 1);                     \
    stage(SM, SB, SS, SKT);                                                         \
    asm volatile("" ::: "memory");                                                  \
    __builtin_amdgcn_s_barrier();                                                   \
    asm volatile("s_waitcnt lgkmcnt(0)" ::: "memory");                              \
    __builtin_amdgcn_sched_barrier(0);                                              \
    __builtin_amdgcn_s_setprio(1);                                                  \
    _Pragma("unroll") for (int m = 0; m < 8; ++m) {                                 \
      acc[m][(NH)*2]   = __builtin_amdgcn_mfma_f32_16x16x32_bf16(af[m], bf0, acc[m][(NH)*2], 0, 0, 0);     \
      acc[m][(NH)*2+1] = __builtin_amdgcn_mfma_f32_16x16x32_bf16(af[m], bf1, acc[m][(NH)*2+1], 0, 0, 0);   \
    }                                                                               \
    __builtin_amdgcn_s_setprio(0);                                                  \
    if (DO_VM) asm volatile("s_waitcnt vmcnt(4)" ::: "memory");                     \
    asm volatile("" ::: "memory");                                                  \
    __builtin_amdgcn_s_barrier();                                                   \
  }

  for (int i = 0; i < 4; ++i) {
    const int kb = 2 * i;
    const int k1 = kb + 1;
    const int k2 = (kb + 2 < 8) ? kb + 2 : 7;
    const int k3 = (kb + 3 < 8) ? kb + 3 : 7;
    PHASE(0, 0, 0, 1, 1, 1, 1, k1, 0)  // ph1: compute buf0/ks0/n01; stage buf1.B-ks1 <- k1
    PHASE(0, 0, 1, 0, 0, 0, 0, k2, 0)  // ph2: buf0/ks0/n23; stage buf0.A-ks0 <- k2
    PHASE(0, 1, 0, 1, 1, 0, 0, k2, 0)  // ph3: buf0/ks1/n01; stage buf0.B-ks0 <- k2
    PHASE(0, 1, 1, 0, 0, 0, 1, k2, 1)  // ph4: buf0/ks1/n23; stage buf0.A-ks1 <- k2; vmcnt(4)
    PHASE(1, 0, 0, 1, 1, 0, 1, k2, 0)  // ph5: buf1/ks0/n01; stage buf0.B-ks1 <- k2
    PHASE(1, 0, 1, 0, 0, 1, 0, k3, 0)  // ph6: buf1/ks0/n23; stage buf1.A-ks0 <- k3
    PHASE(1, 1, 0, 1, 1, 1, 0, k3, 0)  // ph7: buf1/ks1/n01; stage buf1.B-ks0 <- k3
    PHASE(1, 1, 1, 0, 0, 1, 1, k3, 1)  // ph8: buf1/ks1/n23; stage buf1.A-ks1 <- k3; vmcnt(4)
  }
#undef PHASE

  if (QSOFT && bn < 2) {
    #pragma unroll
    for (int m = 0; m < 8; ++m) {
      #pragma unroll
      for (int r = 0; r < 4; ++r) {
        float a0 = acc[m][0][r], a1 = acc[m][1][r], a2 = acc[m][2][r], a3 = acc[m][3][r];
        float mx = fmaxf(fmaxf(a0, a1), fmaxf(a2, a3));
        #pragma unroll
        for (int s = 1; s < 16; s <<= 1) mx = fmaxf(mx, __shfl_xor(mx, s));
        float e0 = __expf(a0 - mx), e1 = __expf(a1 - mx), e2 = __expf(a2 - mx), e3 = __expf(a3 - mx);
        float sum = e0 + e1 + e2 + e3;
        #pragma unroll
        for (int s = 1; s < 16; s <<= 1) sum += __shfl_xor(sum, s);
        float sc = 0.125f / sum;
        acc[m][0][r] = e0 * sc; acc[m][1][r] = e1 * sc;
        acc[m][2][r] = e2 * sc; acc[m][3][r] = e3 * sc;
      }
    }
  }

  #pragma unroll
  for (int m = 0; m < 8; ++m) {
    long row = arow0 + wm * 128 + m * 16 + fq * 4;
    #pragma unroll
    for (int n = 0; n < 4; ++n) {
      long col = brow0 + wn * 64 + n * 16 + fr;
      float bv = BIAS ? bias[col] : 0.0f;
      u16* cp = C + (size_t)row * NOUT + col;
      #pragma unroll
      for (int r = 0; r < 4; ++r)
        cp[(size_t)r * NOUT] = f2b(acc[m][n][r] + bv);
    }
  }
}

// ---------------- spatial k stats: online per-column max/sumexp, coalesced ----------------
__global__ __launch_bounds__(512) void k_kpart(const u16* __restrict__ qkv, float2* __restrict__ part) {
  int bt = blockIdx.x, q = blockIdx.y, c = threadIdx.x;
  const u16* base = qkv + (size_t)(bt * 1024 + q * 128) * 1536 + 512 + c;
  float m = -1e30f, z = 0.f;
  #pragma unroll 4
  for (int n = 0; n < 128; ++n) {
    float v = b2f(base[(size_t)n * 1536]);
    float nm = fmaxf(m, v);
    z = z * __expf(m - nm) + __expf(v - nm);
    m = nm;
  }
  part[(size_t)(bt * 8 + q) * 512 + c] = make_float2(m, z);
}
__global__ __launch_bounds__(512) void k_kred(const float2* __restrict__ part, float2* __restrict__ kst) {
  int bt = blockIdx.x, c = threadIdx.x;
  float2 p[8];
  #pragma unroll
  for (int q = 0; q < 8; ++q) p[q] = part[(size_t)(bt * 8 + q) * 512 + c];
  float M = p[0].x;
  #pragma unroll
  for (int q = 1; q < 8; ++q) M = fmaxf(M, p[q].x);
  float Z = 0.f;
  #pragma unroll
  for (int q = 0; q < 8; ++q) Z += p[q].y * __expf(p[q].x - M);
  kst[(size_t)bt * 512 + c] = make_float2(M, 1.0f / Z);
}

// ---------------- ctx partials via MFMA ----------------
// grid (bt=32, h=8, nc=4); block 256 (4 waves). Each block: n in [nc*256, nc*256+256).
// ctxp[((bt*8+h)*4+nc)*4096 + e*64 + d] = invZ[d] * sum_n exp(K[d][n]-M[d]) * V[e][n]
__global__ __launch_bounds__(256) void k_ctx(const u16* __restrict__ qkv, const float2* __restrict__ kst,
                                             float* __restrict__ ctxp) {
  __shared__ u16 Lraw[64 * 128];   // [n][c]: c 0-63 = K cols, 64-127 = V cols
  __shared__ u16 ET[128 * 64];     // [row][n], XOR-swizzled 16B slots; rows 0-63 Ek(d), 64-127 V(e)
  __shared__ float Ms[64], Zs[64];
  const int bt = blockIdx.x, h = blockIdx.y, nc = blockIdx.z;
  const int tid = threadIdx.x;
  const int wv = tid >> 6, lane = tid & 63;
  const int fr = lane & 15, fq = lane >> 4;
  if (tid < 64) { float2 mz = kst[(size_t)bt * 512 + h * 64 + tid]; Ms[tid] = mz.x; Zs[tid] = mz.y; }

  // staging lane mapping: 16B segment per lane; 4 rows per GLDS16 call
  const int ci = lane & 15;
  const long gcol = (ci < 8) ? (512 + h * 64 + ci * 8) : (1024 + h * 64 + (ci - 8) * 8);
  const long grow0 = (long)bt * 1024 + nc * 256;
  auto stage = [&](int sc) {
    #pragma unroll
    for (int j = 0; j < 4; ++j) {
      int nl = wv * 16 + j * 4 + (lane >> 4);
      const u16* src = qkv + (grow0 + sc * 64 + nl) * 1536 + gcol;
      GLDS16(src, &Lraw[(wv * 16 + j * 4) * 128]);
    }
  };

  // transpose mapping: wave-uniform K/V split
  const int half = tid >> 7;          // 0: K cols, 1: V cols
  const int cpl  = tid & 31;          // col pair
  const int rg   = (tid >> 5) & 3;    // row group (16 n)
  const int c0   = half * 64 + cpl * 2, c1 = c0 + 1;
  const int sw   = (fr >> 1) & 7;     // frag-read slot swizzle

  f32x4 acc[4] = {};
  stage(0);
  for (int sc = 0; sc < 4; ++sc) {
    asm volatile("s_waitcnt vmcnt(0)" ::: "memory");
    __syncthreads();
    // ---- transpose + exp: Lraw[n][c] -> ET[c][n] ----
    {
      u32 w[16];
      #pragma unroll
      for (int j = 0; j < 16; ++j)
        w[j] = *(const u32*)&Lraw[(rg * 16 + j) * 128 + c0];
      u16 o0[16], o1[16];
      if (half == 0) {
        float M0 = Ms[c0], M1 = Ms[c1];
        #pragma unroll
        for (int j = 0; j < 16; ++j) {
          o0[j] = f2b(__expf(__uint_as_float(w[j] << 16) - M0));
          o1[j] = f2b(__expf(__uint_as_float(w[j] & 0xffff0000u) - M1));
        }
      } else {
        #pragma unroll
        for (int j = 0; j < 16; ++j) { o0[j] = (u16)(w[j] & 0xffffu); o1[j] = (u16)(w[j] >> 16); }
      }
      #pragma unroll
      for (int s2 = 0; s2 < 2; ++s2) {
        int phys = (rg * 2 + s2) ^ (cpl & 7);
        uint4 p0 = make_uint4(
            (u32)o0[s2*8+0] | ((u32)o0[s2*8+1] << 16), (u32)o0[s2*8+2] | ((u32)o0[s2*8+3] << 16),
            (u32)o0[s2*8+4] | ((u32)o0[s2*8+5] << 16), (u32)o0[s2*8+6] | ((u32)o0[s2*8+7] << 16));
        uint4 p1 = make_uint4(
            (u32)o1[s2*8+0] | ((u32)o1[s2*8+1] << 16), (u32)o1[s2*8+2] | ((u32)o1[s2*8+3] << 16),
            (u32)o1[s2*8+4] | ((u32)o1[s2*8+5] << 16), (u32)o1[s2*8+6] | ((u32)o1[s2*8+7] << 16));
        *(uint4*)&ET[c0 * 64 + phys * 8] = p0;
        *(uint4*)&ET[c1 * 64 + phys * 8] = p1;
      }
    }
    __syncthreads();
    if (sc < 3) stage(sc + 1);
    // ---- MFMA: wave wv computes d-strip [wv*16, +16) x e[0,64) ----
    {
      short8 afr[2];
      #pragma unroll
      for (int ks = 0; ks < 2; ++ks) {
        int row = wv * 16 + fr;
        afr[ks] = *(const short8*)&ET[row * 64 + ((ks * 4 + fq) ^ sw) * 8];
      }
      #pragma unroll
      for (int nt = 0; nt < 4; ++nt) {
        int row = 64 + nt * 16 + fr;
        #pragma unroll
        for (int ks = 0; ks < 2; ++ks) {
          short8 bfr = *(const short8*)&ET[row * 64 + ((ks * 4 + fq) ^ sw) * 8];
          acc[nt] = __builtin_amdgcn_mfma_f32_16x16x32_bf16(afr[ks], bfr, acc[nt], 0, 0, 0);
        }
      }
    }
    __syncthreads();
  }
  // epilogue: d = wv*16 + fq*4 + r ; e = nt*16 + fr ; apply invZ[d]; store f32 partial [e][d]
  float iz0 = Zs[wv * 16 + fq * 4 + 0], iz1 = Zs[wv * 16 + fq * 4 + 1];
  float iz2 = Zs[wv * 16 + fq * 4 + 2], iz3 = Zs[wv * 16 + fq * 4 + 3];
  size_t cbase = ((size_t)((bt * 8 + h) * 4 + nc)) * 4096;
  #pragma unroll
  for (int nt = 0; nt < 4; ++nt) {
    f32x4 v = acc[nt];
    v[0] *= iz0; v[1] *= iz1; v[2] *= iz2; v[3] *= iz3;
    *(f32x4*)&ctxp[cbase + (size_t)(nt * 16 + fr) * 64 + wv * 16 + fq * 4] = v;
  }
}

// ---------------- out1T[row][h*64+e] = sum_d qs[row][h*64+d] * ctx[d][e]  (MFMA) ----------------
__global__ __launch_bounds__(256) void k_apply(const u16* __restrict__ qkv, const float* __restrict__ ctxp,
                                               u16* __restrict__ out1) {
  __shared__ u16 ct[64 * 72]; // ct[e][d], padded stride 72
  int bh = blockIdx.x; int bt = bh >> 3, h = bh & 7;
  int tid = threadIdx.x; int w = tid >> 6, lane = tid & 63;
  {
    int e = tid >> 2, db = (tid & 3) * 16;
    float s[16] = {};
    size_t pbase = (size_t)bh * 4 * 4096 + (size_t)e * 64 + db;
    #pragma unroll
    for (int ncp = 0; ncp < 4; ++ncp) {
      const float4* p = (const float4*)&ctxp[pbase + (size_t)ncp * 4096];
      #pragma unroll
      for (int j = 0; j < 4; ++j) {
        float4 v = p[j];
        s[j*4+0] += v.x; s[j*4+1] += v.y; s[j*4+2] += v.z; s[j*4+3] += v.w;
      }
    }
    u32 pk[8];
    #pragma unroll
    for (int j = 0; j < 8; ++j) pk[j] = pack2(s[2*j], s[2*j+1]);
    *(uint4*)&ct[e * 72 + db]     = make_uint4(pk[0], pk[1], pk[2], pk[3]);
    *(uint4*)&ct[e * 72 + db + 8] = make_uint4(pk[4], pk[5], pk[6], pk[7]);
  }
  __syncthreads();
  int fr = lane & 15, fq = lane >> 4;
  short8 bfrag[4][2];
  #pragma unroll
  for (int n = 0; n < 4; ++n)
    #pragma unroll
    for (int ks = 0; ks < 2; ++ks)
      bfrag[n][ks] = *(const short8*)&ct[(n * 16 + fr) * 72 + ks * 32 + fq * 8];
  const u16* qbase = qkv + (size_t)(bt * 1024 + w * 256) * 1536 + h * 64;
  for (int mt = 0; mt < 16; ++mt) {
    f32x4 acc[4] = {};
    short8 af[2];
    #pragma unroll
    for (int ks = 0; ks < 2; ++ks)
      af[ks] = *(const short8*)(qbase + (size_t)(mt * 16 + fr) * 1536 + ks * 32 + fq * 8);
    #pragma unroll
    for (int ks = 0; ks < 2; ++ks)
      #pragma unroll
      for (int n = 0; n < 4; ++n)
        acc[n] = __builtin_amdgcn_mfma_f32_16x16x32_bf16(af[ks], bfrag[n][ks], acc[n], 0, 0, 0);
    #pragma unroll
    for (int n = 0; n < 4; ++n) {
      #pragma unroll
      for (int r2 = 0; r2 < 4; ++r2) {
        int row = bt * 1024 + w * 256 + mt * 16 + fq * 4 + r2;
        out1[(size_t)row * 512 + h * 64 + n * 16 + fr] = f2b(acc[n][r2]);
      }
    }
  }
}

// ---------------- temporal attention: per (b,s): 8 heads, 16x16 attn over t, d=64 ----------------
__global__ __launch_bounds__(128) void k_tattn(const u16* __restrict__ qkvt, u16* __restrict__ outbuf) {
  __shared__ u16 L[16 * 1536];
  int bs = blockIdx.x;
  int b = bs >> 10, s = bs & 1023;
  int tid = threadIdx.x;
  {
    int row = tid >> 3, seg = tid & 7;
    const uint4* src = (const uint4*)(qkvt + ((size_t)((b * 16 + row) * 1024 + s)) * 1536 + seg * 192);
    uint4* dst = (uint4*)(L + row * 1536 + seg * 192);
    #pragma unroll
    for (int i = 0; i < 24; ++i) dst[i] = src[i];
  }
  __syncthreads();
  int h = tid >> 4, i = tid & 15;
  const u16* qrow = L + i * 1536 + h * 64;
  float qf[64];
  #pragma unroll
  for (int c = 0; c < 16; ++c) {
    ushort4 u = *(const ushort4*)(qrow + c * 4);
    qf[c*4+0] = b2f(u.x); qf[c*4+1] = b2f(u.y); qf[c*4+2] = b2f(u.z); qf[c*4+3] = b2f(u.w);
  }
  float sim[16];
  #pragma unroll 1
  for (int j = 0; j < 16; ++j) {
    const u16* krow = L + j * 1536 + 512 + h * 64;
    float acc = 0.f;
    #pragma unroll
    for (int c = 0; c < 16; ++c) {
      ushort4 u = *(const ushort4*)(krow + c * 4);
      acc += qf[c*4+0]*b2f(u.x) + qf[c*4+1]*b2f(u.y) + qf[c*4+2]*b2f(u.z) + qf[c*4+3]*b2f(u.w);
    }
    sim[j] = acc * 0.125f;
  }
  float mx = sim[0];
  #pragma unroll
  for (int j = 1; j < 16; ++j) mx = fmaxf(mx, sim[j]);
  float ssum = 0.f;
  #pragma unroll
  for (int j = 0; j < 16; ++j) { sim[j] = __expf(sim[j] - mx); ssum += sim[j]; }
  float inv = 1.0f / ssum;
  float outv[64];
  #pragma unroll
  for (int d = 0; d < 64; ++d) outv[d] = 0.f;
  #pragma unroll 1
  for (int j = 0; j < 16; ++j) {
    float a = sim[j] * inv;
    const u16* vrow = L + j * 1536 + 1024 + h * 64;
    #pragma unroll
    for (int c = 0; c < 16; ++c) {
      ushort4 u = *(const ushort4*)(vrow + c * 4);
      outv[c*4+0] += a * b2f(u.x); outv[c*4+1] += a * b2f(u.y);
      outv[c*4+2] += a * b2f(u.z); outv[c*4+3] += a * b2f(u.w);
    }
  }
  u16* dst = outbuf + ((size_t)((b * 16 + i) * 1024 + s)) * 512 + h * 64;
  #pragma unroll
  for (int c = 0; c < 8; ++c) {
    uint4 o = make_uint4(pack2(outv[c*8+0], outv[c*8+1]), pack2(outv[c*8+2], outv[c*8+3]),
                         pack2(outv[c*8+4], outv[c*8+5]), pack2(outv[c*8+6], outv[c*8+7]));
    ((uint4*)dst)[c] = o;
  }
}

// ---------------- final: out(b,c,t,n) = x + transpose(h2T) ----------------
__global__ __launch_bounds__(256) void k_final(const float* __restrict__ x, const u16* __restrict__ h2T,
                                               float* __restrict__ out) {
  __shared__ u16 tile[64 * 65]; // [c][n]
  int bt = blockIdx.x, c0 = blockIdx.y * 64, n0 = blockIdx.z * 64;
  int b = bt >> 4, t = bt & 15;
  int tid = threadIdx.x;
  {
    int nl = tid >> 2, cs = (tid & 3) * 16;
    const u16* src = h2T + (size_t)(bt * 1024 + n0 + nl) * 512 + c0 + cs;
    uint4 a = ((const uint4*)src)[0], bb = ((const uint4*)src)[1];
    u32 uu[8] = {a.x, a.y, a.z, a.w, bb.x, bb.y, bb.z, bb.w};
    #pragma unroll
    for (int j = 0; j < 8; ++j) {
      tile[(cs + j * 2) * 65 + nl]     = (u16)(uu[j] & 0xffffu);
      tile[(cs + j * 2 + 1) * 65 + nl] = (u16)(uu[j] >> 16);
    }
  }
  __syncthreads();
  const size_t xoff = ((size_t)(b * 512 + c0) * 16 + t) * 1024 + n0;
  #pragma unroll
  for (int it = 0; it < 16; ++it) {
    int cl = it * 4 + (tid >> 6), nl = tid & 63;
    size_t o = xoff + (size_t)cl * 16384 + nl;
    out[o] = x[o] + b2f(tile[cl * 65 + nl]);
  }
}

extern "C" void kernel_launch(void* const* d_in, const int* in_sizes, int n_in,
                              void* d_out, int out_size, void* d_ws, size_t ws_size,
                              hipStream_t stream) {
  const float* x      = (const float*)d_in[0];
  const float* w_sqkv = (const float*)d_in[1];
  const float* w_sout = (const float*)d_in[2];
  const float* b_sout = (const float*)d_in[3];
  const float* w_tqkv = (const float*)d_in[4];
  const float* w_tout = (const float*)d_in[5];
  float* out = (float*)d_out;
  char* ws = (char*)d_ws;

  u16* wsqkv_b = (u16*)(ws + OFF_WSQKV);
  u16* wsout_b = (u16*)(ws + OFF_WSOUT);
  u16* wtqkv_b = (u16*)(ws + OFF_WTQKV);
  u16* wtout_b = (u16*)(ws + OFF_WTOUT);
  float2* kst  = (float2*)(ws + OFF_KST);
  u16* xT      = (u16*)(ws + OFF_XT);   // later reused as h2T
  float* ctxp  = (float*)(ws + OFF_XT); // aliases xT: dead between gemm1 and gemm4
  u16* qkv     = (u16*)(ws + OFF_QKV);  // spatial qkv, later temporal qkv
  u16* mid     = (u16*)(ws + OFF_MID);  // out1T, later attout
  u16* midB    = (u16*)(ws + OFF_MIDB); // h1T
  float2* part = (float2*)(ws + OFF_PART);

  k_cvtw<<<3072, 256, 0, stream>>>(w_sqkv, w_sout, w_tqkv, w_tout, wsqkv_b, wsout_b, wtqkv_b, wtout_b);
  k_xT<<<dim3(32, 8, 16), 256, 0, stream>>>(x, xT);
  gemm8<1536, 0, 1><<<768, 512, 0, stream>>>(xT, wsqkv_b, nullptr, qkv);
  k_kpart<<<dim3(32, 8), 512, 0, stream>>>(qkv, part);
  k_kred<<<32, 512, 0, stream>>>(part, kst);
  k_ctx<<<dim3(32, 8, 4), 256, 0, stream>>>(qkv, kst, ctxp);
  k_apply<<<256, 256, 0, stream>>>(qkv, ctxp, mid);
  gemm8<512, 1, 0><<<256, 512, 0, stream>>>(mid, wsout_b, b_sout, midB);
  gemm8<1536, 0, 0><<<768, 512, 0, stream>>>(midB, wtqkv_b, nullptr, qkv);
  k_tattn<<<2048, 128, 0, stream>>>(qkv, mid);
  gemm8<512, 0, 0><<<256, 512, 0, stream>>>(mid, wtout_b, nullptr, xT);
  k_final<<<dim3(32, 8, 16), 256, 0, stream>>>(x, xT, out);
}

// Round 7
// 437.253 us; speedup vs baseline: 1.4898x; 1.0153x over previous
//
#include <hip/hip_runtime.h>

typedef unsigned short u16;
typedef unsigned int   u32;
typedef __attribute__((ext_vector_type(8))) short short8;
typedef __attribute__((ext_vector_type(4))) float f32x4;

__device__ __forceinline__ u16 f2b(float f) {
  u32 u = __float_as_uint(f);
  return (u16)((u + 0x7FFFu + ((u >> 16) & 1u)) >> 16);
}
__device__ __forceinline__ float b2f(u16 b) { return __uint_as_float((u32)b << 16); }
__device__ __forceinline__ u32 pack2(float a, float b) {
  return (u32)f2b(a) | ((u32)f2b(b) << 16);
}

#define GLDS16(gp, lp) __builtin_amdgcn_global_load_lds( \
    (const __attribute__((address_space(1))) u32*)(gp), \
    (__attribute__((address_space(3))) u32*)(lp), 16, 0, 0)

// ---------------- dims ----------------
// b=2 c=512 t=16 h=32 w=32 ; BT=32 N=1024 ROWS=32768 heads=8 d=64

// ---------------- ws offsets (bytes) ----------------
#define OFF_WSQKV 0UL
#define OFF_WSOUT (OFF_WSQKV + 1536UL*512*2)
#define OFF_WTQKV (OFF_WSOUT + 512UL*512*2)
#define OFF_WTOUT (OFF_WTQKV + 1536UL*512*2)
#define OFF_KST   (OFF_WTOUT + 512UL*512*2)
#define OFF_CTXT  (OFF_KST   + 256UL*64*8)
#define OFF_XT    (OFF_CTXT  + 256UL*64*64*2)
#define OFF_QKV   (OFF_XT    + 32768UL*512*2)
#define OFF_MID   (OFF_QKV   + 32768UL*1536*2)
#define OFF_MIDB  (OFF_MID   + 32768UL*512*2)
#define OFF_PART  (OFF_MIDB  + 32768UL*512*2)
// ctx partials (16MB f32) alias the xT region: xT is dead between gemm1 and gemm4.

// ---------------- weight f32 -> bf16 ----------------
__global__ __launch_bounds__(256) void k_cvtw(const float* ws, const float* wso,
                                              const float* wt, const float* wto,
                                              u16* o1, u16* o2, u16* o3, u16* o4) {
  int i = blockIdx.x * 256 + threadIdx.x;
  if (i < 786432) { o1[i] = f2b(ws[i]); o3[i] = f2b(wt[i]); }
  if (i < 262144) { o2[i] = f2b(wso[i]); o4[i] = f2b(wto[i]); }
}

// ---------------- x (b,c,t,n) f32 -> xT [bt*N+n][c] bf16 ----------------
__global__ __launch_bounds__(256) void k_xT(const float* __restrict__ x, u16* __restrict__ xT) {
  __shared__ u16 tile[64 * 65]; // [c][n]
  int bt = blockIdx.x, c0 = blockIdx.y * 64, n0 = blockIdx.z * 64;
  int b = bt >> 4, t = bt & 15;
  int tid = threadIdx.x;
  const size_t xoff = ((size_t)(b * 512 + c0) * 16 + t) * 1024 + n0;
  #pragma unroll
  for (int it = 0; it < 16; ++it) {
    int cl = it * 4 + (tid >> 6), nl = tid & 63;
    tile[cl * 65 + nl] = f2b(x[xoff + (size_t)cl * 16384 + nl]);
  }
  __syncthreads();
  int nl = tid >> 2, cs = (tid & 3) * 16;
  u32 uu[8];
  #pragma unroll
  for (int j = 0; j < 8; ++j) {
    u32 lo = tile[(cs + j * 2) * 65 + nl];
    u32 hi = tile[(cs + j * 2 + 1) * 65 + nl];
    uu[j] = lo | (hi << 16);
  }
  u16* dst = xT + (size_t)(bt * 1024 + n0 + nl) * 512 + c0 + cs;
  ((uint4*)dst)[0] = make_uint4(uu[0], uu[1], uu[2], uu[3]);
  ((uint4*)dst)[1] = make_uint4(uu[4], uu[5], uu[6], uu[7]);
}

// ---------------- 4-phase 256x256 GEMM: C[row][o] = sum_c A[row][c]*B[o][c] (+bias) ----------------
// 4 fat phases per 2 K-tiles: each phase = 12 ds_read_b128 + 2 stage calls + 32 MFMA.
// vmcnt(8) at every phase end (invariant: 12 outstanding -> lands the stage issued 3 phases ago).
// Epilogue: acc -> LDS (bank-swizzled) -> coalesced dwordx4 stores.
// XCD-aware 1-D grid mapping (T1). QSOFT: bn<2 blocks apply per-(row,head) softmax*0.125.
template <int NOUT, int BIAS, int QSOFT>
__global__ __launch_bounds__(512, 2) void gemm8(const u16* __restrict__ A, const u16* __restrict__ B,
                                                const float* __restrict__ bias, u16* __restrict__ C) {
  constexpr int NBN = NOUT / 256;
  __shared__ u16 lds[65536];
  const int tid = threadIdx.x;
  const int wid = tid >> 6, lane = tid & 63;
  const int wm = wid >> 2, wn = wid & 3;
  const int fr = lane & 15, fq = lane >> 4;
  // XCD-aware block swizzle (bijective: 8 XCDs x 16 bm-chunk x NBN)
  const int xcd = blockIdx.x & 7;
  const int kk_ = blockIdx.x >> 3;            // 0 .. 16*NBN-1
  const int bm = xcd * 16 + kk_ / NBN;
  const int bn = kk_ % NBN;
  const long arow0 = (long)bm * 256, brow0 = (long)bn * 256;

  const int srow  = wid * 16 + (lane >> 2);                 // row 0..127 within load chunk
  const int scol8 = ((lane & 3) ^ ((lane >> 3) & 3)) * 8;   // pre-swizzled col element within 32-col half
  const int rslot = (fq ^ ((fr >> 1) & 3)) * 8;             // swizzled read slot (u16 units)

  auto stage = [&](int mat, int bfi, int s, int kt) {
    const u16* src = (mat == 0 ? A + (arow0 + srow) * 512 : B + (brow0 + srow) * 512)
                     + kt * 64 + s * 32 + scol8;
    int off = ((bfi * 2 + mat) * 2 + s) * 8192 + wid * 512;
    GLDS16(src, &lds[off]);
    GLDS16(src + 128 * 512, &lds[off + 4096]);
  };
  auto ldA = [&](int bfi, int s, int m) -> short8 {
    int row = wm * 128 + m * 16 + fr;
    return *(const short8*)&lds[((bfi * 2 + 0) * 2 + s) * 8192 + row * 32 + rslot];
  };
  auto ldB = [&](int bfi, int s, int n) -> short8 {
    int row = wn * 64 + n * 16 + fr;
    return *(const short8*)&lds[((bfi * 2 + 1) * 2 + s) * 8192 + row * 32 + rslot];
  };

  f32x4 acc[8][4] = {};
  short8 af[8]; short8 bf[4];

  // prologue: buf0 ks0+ks1 <- tile0 ; buf1 ks0 <- tile1  (buf1 ks1 staged in P1 of iter 0)
  stage(0, 0, 0, 0); stage(1, 0, 0, 0);
  stage(0, 0, 1, 0); stage(1, 0, 1, 0);
  stage(0, 1, 0, 1); stage(1, 1, 0, 1);
  asm volatile("s_waitcnt vmcnt(8)" ::: "memory");
  asm volatile("" ::: "memory");
  __builtin_amdgcn_s_barrier();

#define PHASE4(BUFI, S, M1, B1_, S1_, K1_, M2, B2_, S2_, K2_)                        \
  {                                                                                  \
    _Pragma("unroll") for (int m = 0; m < 8; ++m) af[m] = ldA(BUFI, S, m);           \
    _Pragma("unroll") for (int n = 0; n < 4; ++n) bf[n] = ldB(BUFI, S, n);           \
    stage(M1, B1_, S1_, K1_);                                                        \
    stage(M2, B2_, S2_, K2_);                                                        \
    asm volatile("" ::: "memory");                                                   \
    __builtin_amdgcn_s_barrier();                                                    \
    asm volatile("s_waitcnt lgkmcnt(0)" ::: "memory");                               \
    __builtin_amdgcn_sched_barrier(0);                                               \
    __builtin_amdgcn_s_setprio(1);                                                   \
    _Pragma("unroll") for (int m = 0; m < 8; ++m)                                    \
      _Pragma("unroll") for (int n = 0; n < 4; ++n)                                  \
        acc[m][n] = __builtin_amdgcn_mfma_f32_16x16x32_bf16(af[m], bf[n], acc[m][n], 0, 0, 0); \
    __builtin_amdgcn_s_setprio(0);                                                   \
    asm volatile("s_waitcnt vmcnt(8)" ::: "memory");                                 \
    asm volatile("" ::: "memory");                                                   \
    __builtin_amdgcn_s_barrier();                                                    \
  }

  for (int i = 0; i < 4; ++i) {
    const int kb = 2 * i;
    const int k1 = kb + 1;
    const int k2 = (kb + 2 < 8) ? kb + 2 : 7;
    const int k3 = (kb + 3 < 8) ? kb + 3 : 7;
    PHASE4(0, 0, 1, 1, 1, k1, 0, 1, 1, k1)  // compute buf0/ks0 ; stage B1s1<-k1, A1s1<-k1
    PHASE4(0, 1, 0, 0, 0, k2, 1, 0, 0, k2)  // compute buf0/ks1 ; stage A0s0<-k2, B0s0<-k2
    PHASE4(1, 0, 0, 0, 1, k2, 1, 0, 1, k2)  // compute buf1/ks0 ; stage A0s1<-k2, B0s1<-k2
    PHASE4(1, 1, 0, 1, 0, k3, 1, 1, 0, k3)  // compute buf1/ks1 ; stage A1s0<-k3, B1s0<-k3
  }
#undef PHASE4

  if (QSOFT && bn < 2) {
    #pragma unroll
    for (int m = 0; m < 8; ++m) {
      #pragma unroll
      for (int r = 0; r < 4; ++r) {
        float a0 = acc[m][0][r], a1 = acc[m][1][r], a2 = acc[m][2][r], a3 = acc[m][3][r];
        float mx = fmaxf(fmaxf(a0, a1), fmaxf(a2, a3));
        #pragma unroll
        for (int s = 1; s < 16; s <<= 1) mx = fmaxf(mx, __shfl_xor(mx, s));
        float e0 = __expf(a0 - mx), e1 = __expf(a1 - mx), e2 = __expf(a2 - mx), e3 = __expf(a3 - mx);
        float sum = e0 + e1 + e2 + e3;
        #pragma unroll
        for (int s = 1; s < 16; s <<= 1) sum += __shfl_xor(sum, s);
        float sc = 0.125f / sum;
        acc[m][0][r] = e0 * sc; acc[m][1][r] = e1 * sc;
        acc[m][2][r] = e2 * sc; acc[m][3][r] = e3 * sc;
      }
    }
  }

  // ---- epilogue: acc -> LDS (256x256 u16, byte-bits 4-5 XOR'd by (row>>2)&3) -> coalesced stores
  asm volatile("s_waitcnt vmcnt(0)" ::: "memory");
  __syncthreads();
  {
    char* lb = (char*)lds;
    #pragma unroll
    for (int m = 0; m < 8; ++m) {
      int row0 = wm * 128 + m * 16 + fq * 4;
      #pragma unroll
      for (int n = 0; n < 4; ++n) {
        int col = wn * 64 + n * 16 + fr;
        float bv = BIAS ? bias[brow0 + col] : 0.0f;
        #pragma unroll
        for (int r = 0; r < 4; ++r) {
          int row = row0 + r;
          *(u16*)(lb + row * 512 + ((col * 2) ^ (((row >> 2) & 3) << 4))) = f2b(acc[m][n][r] + bv);
        }
      }
    }
  }
  __syncthreads();
  {
    const char* lb = (const char*)lds;
    int seg = tid & 31;
    #pragma unroll
    for (int j = 0; j < 16; ++j) {
      int row = j * 16 + (tid >> 5);
      uint4 v = *(const uint4*)(lb + row * 512 + ((seg * 16) ^ (((row >> 2) & 3) << 4)));
      *(uint4*)(C + (size_t)(arow0 + row) * NOUT + brow0 + seg * 8) = v;
    }
  }
}

// ---------------- spatial k stats: online per-column max/sumexp, coalesced ----------------
__global__ __launch_bounds__(512) void k_kpart(const u16* __restrict__ qkv, float2* __restrict__ part) {
  int bt = blockIdx.x, q = blockIdx.y, c = threadIdx.x;
  const u16* base = qkv + (size_t)(bt * 1024 + q * 128) * 1536 + 512 + c;
  float m = -1e30f, z = 0.f;
  #pragma unroll 4
  for (int n = 0; n < 128; ++n) {
    float v = b2f(base[(size_t)n * 1536]);
    float nm = fmaxf(m, v);
    z = z * __expf(m - nm) + __expf(v - nm);
    m = nm;
  }
  part[(size_t)(bt * 8 + q) * 512 + c] = make_float2(m, z);
}
__global__ __launch_bounds__(512) void k_kred(const float2* __restrict__ part, float2* __restrict__ kst) {
  int bt = blockIdx.x, c = threadIdx.x;
  float2 p[8];
  #pragma unroll
  for (int q = 0; q < 8; ++q) p[q] = part[(size_t)(bt * 8 + q) * 512 + c];
  float M = p[0].x;
  #pragma unroll
  for (int q = 1; q < 8; ++q) M = fmaxf(M, p[q].x);
  float Z = 0.f;
  #pragma unroll
  for (int q = 0; q < 8; ++q) Z += p[q].y * __expf(p[q].x - M);
  kst[(size_t)bt * 512 + c] = make_float2(M, 1.0f / Z);
}

// ---------------- ctx partials via MFMA ----------------
// grid (bt=32, h=8, nc=4); block 256 (4 waves). Each block: n in [nc*256, nc*256+256).
// ctxp[((bt*8+h)*4+nc)*4096 + e*64 + d] = invZ[d] * sum_n exp(K[d][n]-M[d]) * V[e][n]
__global__ __launch_bounds__(256) void k_ctx(const u16* __restrict__ qkv, const float2* __restrict__ kst,
                                             float* __restrict__ ctxp) {
  __shared__ u16 Lraw[64 * 128];   // [n][c]: c 0-63 = K cols, 64-127 = V cols
  __shared__ u16 ET[128 * 64];     // [row][n], XOR-swizzled 16B slots; rows 0-63 Ek(d), 64-127 V(e)
  __shared__ float Ms[64], Zs[64];
  const int bt = blockIdx.x, h = blockIdx.y, nc = blockIdx.z;
  const int tid = threadIdx.x;
  const int wv = tid >> 6, lane = tid & 63;
  const int fr = lane & 15, fq = lane >> 4;
  if (tid < 64) { float2 mz = kst[(size_t)bt * 512 + h * 64 + tid]; Ms[tid] = mz.x; Zs[tid] = mz.y; }

  // staging lane mapping: 16B segment per lane; 4 rows per GLDS16 call
  const int ci = lane & 15;
  const long gcol = (ci < 8) ? (512 + h * 64 + ci * 8) : (1024 + h * 64 + (ci - 8) * 8);
  const long grow0 = (long)bt * 1024 + nc * 256;
  auto stage = [&](int sc) {
    #pragma unroll
    for (int j = 0; j < 4; ++j) {
      int nl = wv * 16 + j * 4 + (lane >> 4);
      const u16* src = qkv + (grow0 + sc * 64 + nl) * 1536 + gcol;
      GLDS16(src, &Lraw[(wv * 16 + j * 4) * 128]);
    }
  };

  // transpose mapping: wave-uniform K/V split
  const int half = tid >> 7;          // 0: K cols, 1: V cols
  const int cpl  = tid & 31;          // col pair
  const int rg   = (tid >> 5) & 3;    // row group (16 n)
  const int c0   = half * 64 + cpl * 2, c1 = c0 + 1;
  const int sw   = (fr >> 1) & 7;     // frag-read slot swizzle

  f32x4 acc[4] = {};
  stage(0);
  for (int sc = 0; sc < 4; ++sc) {
    asm volatile("s_waitcnt vmcnt(0)" ::: "memory");
    __syncthreads();
    // ---- transpose + exp: Lraw[n][c] -> ET[c][n] ----
    {
      u32 w[16];
      #pragma unroll
      for (int j = 0; j < 16; ++j)
        w[j] = *(const u32*)&Lraw[(rg * 16 + j) * 128 + c0];
      u16 o0[16], o1[16];
      if (half == 0) {
        float M0 = Ms[c0], M1 = Ms[c1];
        #pragma unroll
        for (int j = 0; j < 16; ++j) {
          o0[j] = f2b(__expf(__uint_as_float(w[j] << 16) - M0));
          o1[j] = f2b(__expf(__uint_as_float(w[j] & 0xffff0000u) - M1));
        }
      } else {
        #pragma unroll
        for (int j = 0; j < 16; ++j) { o0[j] = (u16)(w[j] & 0xffffu); o1[j] = (u16)(w[j] >> 16); }
      }
      #pragma unroll
      for (int s2 = 0; s2 < 2; ++s2) {
        int phys = (rg * 2 + s2) ^ (cpl & 7);
        uint4 p0 = make_uint4(
            (u32)o0[s2*8+0] | ((u32)o0[s2*8+1] << 16), (u32)o0[s2*8+2] | ((u32)o0[s2*8+3] << 16),
            (u32)o0[s2*8+4] | ((u32)o0[s2*8+5] << 16), (u32)o0[s2*8+6] | ((u32)o0[s2*8+7] << 16));
        uint4 p1 = make_uint4(
            (u32)o1[s2*8+0] | ((u32)o1[s2*8+1] << 16), (u32)o1[s2*8+2] | ((u32)o1[s2*8+3] << 16),
            (u32)o1[s2*8+4] | ((u32)o1[s2*8+5] << 16), (u32)o1[s2*8+6] | ((u32)o1[s2*8+7] << 16));
        *(uint4*)&ET[c0 * 64 + phys * 8] = p0;
        *(uint4*)&ET[c1 * 64 + phys * 8] = p1;
      }
    }
    __syncthreads();
    if (sc < 3) stage(sc + 1);
    // ---- MFMA: wave wv computes d-strip [wv*16, +16) x e[0,64) ----
    {
      short8 afr[2];
      #pragma unroll
      for (int ks = 0; ks < 2; ++ks) {
        int row = wv * 16 + fr;
        afr[ks] = *(const short8*)&ET[row * 64 + ((ks * 4 + fq) ^ sw) * 8];
      }
      #pragma unroll
      for (int nt = 0; nt < 4; ++nt) {
        int row = 64 + nt * 16 + fr;
        #pragma unroll
        for (int ks = 0; ks < 2; ++ks) {
          short8 bfr = *(const short8*)&ET[row * 64 + ((ks * 4 + fq) ^ sw) * 8];
          acc[nt] = __builtin_amdgcn_mfma_f32_16x16x32_bf16(afr[ks], bfr, acc[nt], 0, 0, 0);
        }
      }
    }
    __syncthreads();
  }
  // epilogue: d = wv*16 + fq*4 + r ; e = nt*16 + fr ; apply invZ[d]; store f32 partial [e][d]
  float iz0 = Zs[wv * 16 + fq * 4 + 0], iz1 = Zs[wv * 16 + fq * 4 + 1];
  float iz2 = Zs[wv * 16 + fq * 4 + 2], iz3 = Zs[wv * 16 + fq * 4 + 3];
  size_t cbase = ((size_t)((bt * 8 + h) * 4 + nc)) * 4096;
  #pragma unroll
  for (int nt = 0; nt < 4; ++nt) {
    f32x4 v = acc[nt];
    v[0] *= iz0; v[1] *= iz1; v[2] *= iz2; v[3] *= iz3;
    *(f32x4*)&ctxp[cbase + (size_t)(nt * 16 + fr) * 64 + wv * 16 + fq * 4] = v;
  }
}

// ---------------- out1T[row][h*64+e] = sum_d qs[row][h*64+d] * ctx[d][e]  (MFMA) ----------------
__global__ __launch_bounds__(256) void k_apply(const u16* __restrict__ qkv, const float* __restrict__ ctxp,
                                               u16* __restrict__ out1) {
  __shared__ u16 ct[64 * 72]; // ct[e][d], padded stride 72
  int bh = blockIdx.x; int bt = bh >> 3, h = bh & 7;
  int tid = threadIdx.x; int w = tid >> 6, lane = tid & 63;
  {
    int e = tid >> 2, db = (tid & 3) * 16;
    float s[16] = {};
    size_t pbase = (size_t)bh * 4 * 4096 + (size_t)e * 64 + db;
    #pragma unroll
    for (int ncp = 0; ncp < 4; ++ncp) {
      const float4* p = (const float4*)&ctxp[pbase + (size_t)ncp * 4096];
      #pragma unroll
      for (int j = 0; j < 4; ++j) {
        float4 v = p[j];
        s[j*4+0] += v.x; s[j*4+1] += v.y; s[j*4+2] += v.z; s[j*4+3] += v.w;
      }
    }
    u32 pk[8];
    #pragma unroll
    for (int j = 0; j < 8; ++j) pk[j] = pack2(s[2*j], s[2*j+1]);
    *(uint4*)&ct[e * 72 + db]     = make_uint4(pk[0], pk[1], pk[2], pk[3]);
    *(uint4*)&ct[e * 72 + db + 8] = make_uint4(pk[4], pk[5], pk[6], pk[7]);
  }
  __syncthreads();
  int fr = lane & 15, fq = lane >> 4;
  short8 bfrag[4][2];
  #pragma unroll
  for (int n = 0; n < 4; ++n)
    #pragma unroll
    for (int ks = 0; ks < 2; ++ks)
      bfrag[n][ks] = *(const short8*)&ct[(n * 16 + fr) * 72 + ks * 32 + fq * 8];
  const u16* qbase = qkv + (size_t)(bt * 1024 + w * 256) * 1536 + h * 64;
  for (int mt = 0; mt < 16; ++mt) {
    f32x4 acc[4] = {};
    short8 af[2];
    #pragma unroll
    for (int ks = 0; ks < 2; ++ks)
      af[ks] = *(const short8*)(qbase + (size_t)(mt * 16 + fr) * 1536 + ks * 32 + fq * 8);
    #pragma unroll
    for (int ks = 0; ks < 2; ++ks)
      #pragma unroll
      for (int n = 0; n < 4; ++n)
        acc[n] = __builtin_amdgcn_mfma_f32_16x16x32_bf16(af[ks], bfrag[n][ks], acc[n], 0, 0, 0);
    #pragma unroll
    for (int n = 0; n < 4; ++n) {
      #pragma unroll
      for (int r2 = 0; r2 < 4; ++r2) {
        int row = bt * 1024 + w * 256 + mt * 16 + fq * 4 + r2;
        out1[(size_t)row * 512 + h * 64 + n * 16 + fr] = f2b(acc[n][r2]);
      }
    }
  }
}

// ---------------- temporal attention: per (b,s): 8 heads, 16x16 attn over t, d=64 ----------------
__global__ __launch_bounds__(128) void k_tattn(const u16* __restrict__ qkvt, u16* __restrict__ outbuf) {
  __shared__ u16 L[16 * 1536];
  int bs = blockIdx.x;
  int b = bs >> 10, s = bs & 1023;
  int tid = threadIdx.x;
  {
    int row = tid >> 3, seg = tid & 7;
    const uint4* src = (const uint4*)(qkvt + ((size_t)((b * 16 + row) * 1024 + s)) * 1536 + seg * 192);
    uint4* dst = (uint4*)(L + row * 1536 + seg * 192);
    #pragma unroll
    for (int i = 0; i < 24; ++i) dst[i] = src[i];
  }
  __syncthreads();
  int h = tid >> 4, i = tid & 15;
  const u16* qrow = L + i * 1536 + h * 64;
  float qf[64];
  #pragma unroll
  for (int c = 0; c < 16; ++c) {
    ushort4 u = *(const ushort4*)(qrow + c * 4);
    qf[c*4+0] = b2f(u.x); qf[c*4+1] = b2f(u.y); qf[c*4+2] = b2f(u.z); qf[c*4+3] = b2f(u.w);
  }
  float sim[16];
  #pragma unroll 1
  for (int j = 0; j < 16; ++j) {
    const u16* krow = L + j * 1536 + 512 + h * 64;
    float acc = 0.f;
    #pragma unroll
    for (int c = 0; c < 16; ++c) {
      ushort4 u = *(const ushort4*)(krow + c * 4);
      acc += qf[c*4+0]*b2f(u.x) + qf[c*4+1]*b2f(u.y) + qf[c*4+2]*b2f(u.z) + qf[c*4+3]*b2f(u.w);
    }
    sim[j] = acc * 0.125f;
  }
  float mx = sim[0];
  #pragma unroll
  for (int j = 1; j < 16; ++j) mx = fmaxf(mx, sim[j]);
  float ssum = 0.f;
  #pragma unroll
  for (int j = 0; j < 16; ++j) { sim[j] = __expf(sim[j] - mx); ssum += sim[j]; }
  float inv = 1.0f / ssum;
  float outv[64];
  #pragma unroll
  for (int d = 0; d < 64; ++d) outv[d] = 0.f;
  #pragma unroll 1
  for (int j = 0; j < 16; ++j) {
    float a = sim[j] * inv;
    const u16* vrow = L + j * 1536 + 1024 + h * 64;
    #pragma unroll
    for (int c = 0; c < 16; ++c) {
      ushort4 u = *(const ushort4*)(vrow + c * 4);
      outv[c*4+0] += a * b2f(u.x); outv[c*4+1] += a * b2f(u.y);
      outv[c*4+2] += a * b2f(u.z); outv[c*4+3] += a * b2f(u.w);
    }
  }
  u16* dst = outbuf + ((size_t)((b * 16 + i) * 1024 + s)) * 512 + h * 64;
  #pragma unroll
  for (int c = 0; c < 8; ++c) {
    uint4 o = make_uint4(pack2(outv[c*8+0], outv[c*8+1]), pack2(outv[c*8+2], outv[c*8+3]),
                         pack2(outv[c*8+4], outv[c*8+5]), pack2(outv[c*8+6], outv[c*8+7]));
    ((uint4*)dst)[c] = o;
  }
}

// ---------------- final: out(b,c,t,n) = x + transpose(h2T) ----------------
__global__ __launch_bounds__(256) void k_final(const float* __restrict__ x, const u16* __restrict__ h2T,
                                               float* __restrict__ out) {
  __shared__ u16 tile[64 * 65]; // [c][n]
  int bt = blockIdx.x, c0 = blockIdx.y * 64, n0 = blockIdx.z * 64;
  int b = bt >> 4, t = bt & 15;
  int tid = threadIdx.x;
  {
    int nl = tid >> 2, cs = (tid & 3) * 16;
    const u16* src = h2T + (size_t)(bt * 1024 + n0 + nl) * 512 + c0 + cs;
    uint4 a = ((const uint4*)src)[0], bb = ((const uint4*)src)[1];
    u32 uu[8] = {a.x, a.y, a.z, a.w, bb.x, bb.y, bb.z, bb.w};
    #pragma unroll
    for (int j = 0; j < 8; ++j) {
      tile[(cs + j * 2) * 65 + nl]     = (u16)(uu[j] & 0xffffu);
      tile[(cs + j * 2 + 1) * 65 + nl] = (u16)(uu[j] >> 16);
    }
  }
  __syncthreads();
  const size_t xoff = ((size_t)(b * 512 + c0) * 16 + t) * 1024 + n0;
  #pragma unroll
  for (int it = 0; it < 16; ++it) {
    int cl = it * 4 + (tid >> 6), nl = tid & 63;
    size_t o = xoff + (size_t)cl * 16384 + nl;
    out[o] = x[o] + b2f(tile[cl * 65 + nl]);
  }
}

extern "C" void kernel_launch(void* const* d_in, const int* in_sizes, int n_in,
                              void* d_out, int out_size, void* d_ws, size_t ws_size,
                              hipStream_t stream) {
  const float* x      = (const float*)d_in[0];
  const float* w_sqkv = (const float*)d_in[1];
  const float* w_sout = (const float*)d_in[2];
  const float* b_sout = (const float*)d_in[3];
  const float* w_tqkv = (const float*)d_in[4];
  const float* w_tout = (const float*)d_in[5];
  float* out = (float*)d_out;
  char* ws = (char*)d_ws;

  u16* wsqkv_b = (u16*)(ws + OFF_WSQKV);
  u16* wsout_b = (u16*)(ws + OFF_WSOUT);
  u16* wtqkv_b = (u16*)(ws + OFF_WTQKV);
  u16* wtout_b = (u16*)(ws + OFF_WTOUT);
  float2* kst  = (float2*)(ws + OFF_KST);
  u16* xT      = (u16*)(ws + OFF_XT);   // later reused as h2T
  float* ctxp  = (float*)(ws + OFF_XT); // aliases xT: dead between gemm1 and gemm4
  u16* qkv     = (u16*)(ws + OFF_QKV);  // spatial qkv, later temporal qkv
  u16* mid     = (u16*)(ws + OFF_MID);  // out1T, later attout
  u16* midB    = (u16*)(ws + OFF_MIDB); // h1T
  float2* part = (float2*)(ws + OFF_PART);

  k_cvtw<<<3072, 256, 0, stream>>>(w_sqkv, w_sout, w_tqkv, w_tout, wsqkv_b, wsout_b, wtqkv_b, wtout_b);
  k_xT<<<dim3(32, 8, 16), 256, 0, stream>>>(x, xT);
  gemm8<1536, 0, 1><<<768, 512, 0, stream>>>(xT, wsqkv_b, nullptr, qkv);
  k_kpart<<<dim3(32, 8), 512, 0, stream>>>(qkv, part);
  k_kred<<<32, 512, 0, stream>>>(part, kst);
  k_ctx<<<dim3(32, 8, 4), 256, 0, stream>>>(qkv, kst, ctxp);
  k_apply<<<256, 256, 0, stream>>>(qkv, ctxp, mid);
  gemm8<512, 1, 0><<<256, 512, 0, stream>>>(mid, wsout_b, b_sout, midB);
  gemm8<1536, 0, 0><<<768, 512, 0, stream>>>(midB, wtqkv_b, nullptr, qkv);
  k_tattn<<<2048, 128, 0, stream>>>(qkv, mid);
  gemm8<512, 0, 0><<<256, 512, 0, stream>>>(mid, wtout_b, nullptr, xT);
  k_final<<<dim3(32, 8, 16), 256, 0, stream>>>(x, xT, out);
}